// Round 3
// baseline (327.605 us; speedup 1.0000x reference)
//
#include <hip/hip_runtime.h>
#include <stdint.h>

// ImportanceSparsification: per-batch top-k (k = 0.2*S*T) of 1/(cost+1e-8),
// out = (source, target, cost*mask). Exact selection on importance f32 bit
// patterns with jax top_k tie-break (lowest flat index among equals).
//
// R2 -> R3: radix-select on importance bits had massive LDS-atomic
// serialization (importance distribution concentrates ~11% in one bin).
// Since importance is monotone non-increasing in cost, select on a LINEAR
// cost-value histogram (uniform input -> flat bins -> no contention), then
// resolve the exact importance-bit threshold + tie index from ~770 boundary
// candidates in one small block. 5 full passes -> 3.

static constexpr int HBINS = 4096;   // linear cost bins
static constexpr int CAP   = 4096;   // candidate buffer per batch
static constexpr float EPSF = 1e-8f;

__device__ __forceinline__ uint32_t impBits(float c) {
    // IEEE-correct f32 ops (no fast-math) -> bit-exact vs numpy reference
    return __float_as_uint(1.0f / (c + EPSF));
}

__device__ __forceinline__ uint32_t costBin(float x) {
    uint32_t bi = (uint32_t)(x * 4096.0f);   // x >= 0 (uniform [0,1))
    return bi > (HBINS - 1) ? (HBINS - 1) : bi;
}

// meta per batch (16 u32):
// [0]=lo_bin [1]=hi_bin [2]=t [3]=base [4]=candcnt [5]=idxthr

__global__ __launch_bounds__(256) void histc_kernel(
    const float4* __restrict__ cost4, uint32_t* __restrict__ hist, int n4) {
    __shared__ uint32_t lh[HBINS];
    const int b = blockIdx.y;
    for (int i = threadIdx.x; i < HBINS; i += 256) lh[i] = 0;
    __syncthreads();
    const int idx = blockIdx.x * 256 + threadIdx.x;
    float4 v = cost4[(size_t)b * n4 + idx];
    atomicAdd(&lh[costBin(v.x)], 1u);
    atomicAdd(&lh[costBin(v.y)], 1u);
    atomicAdd(&lh[costBin(v.z)], 1u);
    atomicAdd(&lh[costBin(v.w)], 1u);
    __syncthreads();
    uint32_t* gh = hist + (size_t)b * HBINS;
    for (int i = threadIdx.x; i < HBINS; i += 256)
        if (lh[i]) atomicAdd(&gh[i], lh[i]);
}

// One block per batch: ascending prefix scan, find bin q where the K-th
// smallest cost lies; store candidate bin range [q-1, q+1] and base count.
__global__ __launch_bounds__(256) void scan_kernel(
    const uint32_t* __restrict__ hist, uint32_t* __restrict__ meta, uint32_t K) {
    const int b = blockIdx.x;
    const uint32_t* h = hist + (size_t)b * HBINS;
    __shared__ uint32_t s[256];
    const int t = threadIdx.x;
    uint32_t hv[HBINS / 256];
    uint32_t csum = 0;
    for (int i = 0; i < HBINS / 256; ++i) { hv[i] = h[t * (HBINS / 256) + i]; csum += hv[i]; }
    s[t] = csum;
    __syncthreads();
    // inclusive ascending prefix scan (Hillis-Steele)
    for (int off = 1; off < 256; off <<= 1) {
        uint32_t add = (t >= off) ? s[t - off] : 0u;
        uint32_t cur = s[t];
        __syncthreads();
        s[t] = cur + add;
        __syncthreads();
    }
    const uint32_t before = s[t] - csum;  // count of bins in chunks < mine
    if (before < K && s[t] >= K) {
        uint32_t cum = before;
        for (int i = 0; i < HBINS / 256; ++i) {
            const uint32_t c = hv[i];
            if (cum + c >= K) {
                const uint32_t q = (uint32_t)(t * (HBINS / 256) + i);
                const uint32_t lo = (q > 0) ? q - 1 : 0;
                const uint32_t hi = (q < HBINS - 1) ? q + 1 : (HBINS - 1);
                // base = count of elements in bins < lo
                const uint32_t base = cum - ((q > 0) ? h[q - 1] : 0u);
                meta[b * 16 + 0] = lo;
                meta[b * 16 + 1] = hi;
                meta[b * 16 + 3] = base;
                break;
            }
            cum += c;
        }
    }
}

__global__ __launch_bounds__(256) void gathercand_kernel(
    const float4* __restrict__ cost4, uint32_t* __restrict__ meta,
    uint32_t* __restrict__ candv, uint32_t* __restrict__ candi, int n4) {
    const int b = blockIdx.y;
    const uint32_t lo = meta[b * 16 + 0];
    const uint32_t hi = meta[b * 16 + 1];
    const int idx = blockIdx.x * 256 + threadIdx.x;
    float4 v = cost4[(size_t)b * n4 + idx];
    const uint32_t base = (uint32_t)idx * 4u;
    uint32_t* cv = candv + (size_t)b * CAP;
    uint32_t* ci = candi + (size_t)b * CAP;
    const float x[4] = {v.x, v.y, v.z, v.w};
    #pragma unroll
    for (int j = 0; j < 4; ++j) {
        const uint32_t bi = costBin(x[j]);
        if (bi >= lo && bi <= hi) {
            const uint32_t p = atomicAdd(&meta[b * 16 + 4], 1u);
            if (p < (uint32_t)CAP) {
                cv[p] = __float_as_uint(x[j]);
                ci[p] = base + (uint32_t)j;
            }
        }
    }
}

// One block per batch: from ~770 candidates, find exact importance-bit
// threshold t and tie-break index. All counting is order-independent.
__global__ __launch_bounds__(256) void solve_kernel(
    uint32_t* __restrict__ meta, const uint32_t* __restrict__ candv,
    const uint32_t* __restrict__ candi, uint32_t K, int N) {
    const int b = blockIdx.x;
    uint32_t* mb = meta + b * 16;
    const uint32_t cnt0 = mb[4];
    const uint32_t cnt = (cnt0 > (uint32_t)CAP) ? (uint32_t)CAP : cnt0;
    const uint32_t base = mb[3];
    const uint32_t need = K - base;  // rank of c_(K) within candidates (1-based)
    const uint32_t* cv = candv + (size_t)b * CAP;
    const uint32_t* ci = candi + (size_t)b * CAP;
    __shared__ uint32_t s[256];
    const int t = threadIdx.x;

    // 1) binary search: smallest cost-bit value v with count(cbits <= v) >= need
    uint32_t lo = 0u, hi = 0xFFFFFFFFu;
    while (lo < hi) {
        const uint32_t mid = lo + ((hi - lo) >> 1);
        uint32_t c = 0;
        for (uint32_t j = t; j < cnt; j += 256) c += (cv[j] <= mid) ? 1u : 0u;
        s[t] = c;
        __syncthreads();
        for (int st = 128; st > 0; st >>= 1) {
            if (t < st) s[t] += s[t + st];
            __syncthreads();
        }
        const uint32_t tot = s[0];
        __syncthreads();
        if (tot >= need) hi = mid; else lo = mid + 1;
    }
    const uint32_t thr = impBits(__uint_as_float(lo));

    // 2) count candidates with imp > thr and == thr
    uint32_t cg = 0, ce = 0;
    for (uint32_t j = t; j < cnt; j += 256) {
        const uint32_t ib = impBits(__uint_as_float(cv[j]));
        cg += (ib > thr) ? 1u : 0u;
        ce += (ib == thr) ? 1u : 0u;
    }
    s[t] = cg;
    __syncthreads();
    for (int st = 128; st > 0; st >>= 1) {
        if (t < st) s[t] += s[t + st];
        __syncthreads();
    }
    const uint32_t gt = s[0];
    __syncthreads();
    s[t] = ce;
    __syncthreads();
    for (int st = 128; st > 0; st >>= 1) {
        if (t < st) s[t] += s[t + st];
        __syncthreads();
    }
    const uint32_t eq = s[0];
    __syncthreads();

    const uint32_t m = K - base - gt;  // # of threshold-equal elements to take
    uint32_t idxthr = 0xFFFFFFFFu;
    if (m < eq) {
        // 3) m-th smallest flat index among equals (binary search on index)
        uint32_t l2 = 0u, h2 = (uint32_t)N - 1u;
        while (l2 < h2) {
            const uint32_t mid = (l2 + h2) >> 1;
            uint32_t c = 0;
            for (uint32_t j = t; j < cnt; j += 256)
                c += (impBits(__uint_as_float(cv[j])) == thr && ci[j] <= mid) ? 1u : 0u;
            s[t] = c;
            __syncthreads();
            for (int st = 128; st > 0; st >>= 1) {
                if (t < st) s[t] += s[t + st];
                __syncthreads();
            }
            const uint32_t tot = s[0];
            __syncthreads();
            if (tot >= m) h2 = mid; else l2 = mid + 1;
        }
        idxthr = l2;
    }
    if (t == 0) { mb[2] = thr; mb[5] = idxthr; }
}

__global__ __launch_bounds__(256) void final_kernel(
    const float4* __restrict__ cost4, float4* __restrict__ out4,
    const uint32_t* __restrict__ meta, int n4) {
    const int b = blockIdx.y;
    const uint32_t t = meta[b * 16 + 2];
    const uint32_t idxthr = meta[b * 16 + 5];
    const int idx = blockIdx.x * 256 + threadIdx.x;
    const size_t off = (size_t)b * n4 + idx;
    float4 v = cost4[off];
    const uint32_t base = (uint32_t)idx * 4u;
    float4 r;
    uint32_t bx;
    bx = impBits(v.x); r.x = (bx > t || (bx == t && base + 0 <= idxthr)) ? v.x : 0.0f;
    bx = impBits(v.y); r.y = (bx > t || (bx == t && base + 1 <= idxthr)) ? v.y : 0.0f;
    bx = impBits(v.z); r.z = (bx > t || (bx == t && base + 2 <= idxthr)) ? v.z : 0.0f;
    bx = impBits(v.w); r.w = (bx > t || (bx == t && base + 3 <= idxthr)) ? v.w : 0.0f;
    out4[off] = r;
}

extern "C" void kernel_launch(void* const* d_in, const int* in_sizes, int n_in,
                              void* d_out, int out_size, void* d_ws, size_t ws_size,
                              hipStream_t stream) {
    const float* src  = (const float*)d_in[0];
    const float* tgt  = (const float*)d_in[1];
    const float* cost = (const float*)d_in[2];
    const int srcN = in_sizes[0];
    const int tgtN = in_sizes[1];
    const int costN = in_sizes[2];
    const int S = 1024, T = 1024;
    const int N = S * T;
    const int B = costN / N;
    const uint32_t K = (uint32_t)(((uint64_t)N * 2ull) / 10ull);  // int(N*0.2)

    float* out = (float*)d_out;
    hipMemcpyAsync(out, src, sizeof(float) * (size_t)srcN,
                   hipMemcpyDeviceToDevice, stream);
    hipMemcpyAsync(out + srcN, tgt, sizeof(float) * (size_t)tgtN,
                   hipMemcpyDeviceToDevice, stream);
    float* outCost = out + (size_t)srcN + tgtN;

    uint32_t* hist  = (uint32_t*)d_ws;
    uint32_t* meta  = hist + (size_t)B * HBINS;
    uint32_t* candv = meta + (size_t)B * 16;
    uint32_t* candi = candv + (size_t)B * CAP;
    const size_t zeroBytes = sizeof(uint32_t) * ((size_t)B * (HBINS + 16));
    hipMemsetAsync(d_ws, 0, zeroBytes, stream);

    const int n4 = N / 4;
    dim3 blk(256, 1, 1);
    dim3 grid(n4 / 256, B, 1);

    histc_kernel<<<grid, blk, 0, stream>>>((const float4*)cost, hist, n4);
    scan_kernel<<<B, 256, 0, stream>>>(hist, meta, K);
    gathercand_kernel<<<grid, blk, 0, stream>>>((const float4*)cost, meta, candv, candi, n4);
    solve_kernel<<<B, 256, 0, stream>>>(meta, candv, candi, K, N);
    final_kernel<<<grid, blk, 0, stream>>>((const float4*)cost, (float4*)outCost, meta, n4);
}

// Round 4
// 177.560 us; speedup vs baseline: 1.8450x; 1.8450x over previous
//
#include <hip/hip_runtime.h>
#include <stdint.h>

// ImportanceSparsification: per-batch top-k (k = 0.2*S*T) of 1/(cost+1e-8),
// out = (source, target, cost*mask). Exact selection with jax top_k
// tie-break (lowest flat index among equal importance values).
//
// R3 -> R4: histc flush was 13M global atomics (16384 tiny blocks x 4096
// bins, ~1 atomic per sample). Fix aggregation ratio: 512 bins, 64 fat
// blocks/batch (16K samples/block -> 32 samples/bin amortization).
// Gather: LDS staging + one reservation atomic per block (kills
// same-address L2 atomic serialization on the per-batch counter).
// Solve: candidates staged in LDS, binary search bounded to candidate-bin
// bit range.

static constexpr int HBINS = 512;    // linear cost bins
static constexpr int CAP   = 16384;  // per-batch candidate cap (global)
static constexpr int LCAP  = 2048;   // per-block candidate staging (LDS)
static constexpr int LDSCV = 12288;  // solve: LDS-staged candidate values
static constexpr float EPSF = 1e-8f;

__device__ __forceinline__ uint32_t impBits(float c) {
    // IEEE-correct f32 ops (no fast-math) -> bit-exact vs numpy reference
    return __float_as_uint(1.0f / (c + EPSF));
}

__device__ __forceinline__ uint32_t costBin(float x) {
    uint32_t bi = (uint32_t)(x * (float)HBINS);  // x in [0,1)
    return bi > (HBINS - 1) ? (HBINS - 1) : bi;
}

// meta per batch (16 u32):
// [0]=lo_bin [1]=hi_bin [2]=t [3]=base [4]=candcnt [5]=idxthr

__global__ __launch_bounds__(256) void histc_kernel(
    const float4* __restrict__ cost4, uint32_t* __restrict__ hist,
    int n4, int f4pb) {
    __shared__ uint32_t lh[HBINS];
    const int b = blockIdx.y;
    for (int i = threadIdx.x; i < HBINS; i += 256) lh[i] = 0;
    __syncthreads();
    const size_t base = (size_t)b * n4 + (size_t)blockIdx.x * f4pb;
    const int iters = f4pb / 256;
    for (int it = 0; it < iters; ++it) {
        float4 v = cost4[base + it * 256 + threadIdx.x];
        atomicAdd(&lh[costBin(v.x)], 1u);
        atomicAdd(&lh[costBin(v.y)], 1u);
        atomicAdd(&lh[costBin(v.z)], 1u);
        atomicAdd(&lh[costBin(v.w)], 1u);
    }
    __syncthreads();
    uint32_t* gh = hist + (size_t)b * HBINS;
    for (int i = threadIdx.x; i < HBINS; i += 256)
        if (lh[i]) atomicAdd(&gh[i], lh[i]);
}

// One block per batch: ascending prefix scan over 512 bins, find bin q
// containing the K-th smallest cost; candidate range [q-1, q+1].
__global__ __launch_bounds__(256) void scan_kernel(
    const uint32_t* __restrict__ hist, uint32_t* __restrict__ meta, uint32_t K) {
    const int b = blockIdx.x;
    const uint32_t* h = hist + (size_t)b * HBINS;
    __shared__ uint32_t s[256];
    const int t = threadIdx.x;
    const int C = HBINS / 256;  // 2
    uint32_t hv[C];
    uint32_t csum = 0;
    for (int i = 0; i < C; ++i) { hv[i] = h[t * C + i]; csum += hv[i]; }
    s[t] = csum;
    __syncthreads();
    for (int off = 1; off < 256; off <<= 1) {
        uint32_t add = (t >= off) ? s[t - off] : 0u;
        uint32_t cur = s[t];
        __syncthreads();
        s[t] = cur + add;
        __syncthreads();
    }
    const uint32_t before = s[t] - csum;
    if (before < K && s[t] >= K) {
        uint32_t cum = before;
        for (int i = 0; i < C; ++i) {
            const uint32_t c = hv[i];
            if (cum + c >= K) {
                const uint32_t q = (uint32_t)(t * C + i);
                const uint32_t lo = (q > 0) ? q - 1 : 0;
                const uint32_t hi = (q < HBINS - 1) ? q + 1 : (HBINS - 1);
                const uint32_t base = cum - ((q > 0) ? h[q - 1] : 0u);
                meta[b * 16 + 0] = lo;
                meta[b * 16 + 1] = hi;
                meta[b * 16 + 3] = base;
                break;
            }
            cum += c;
        }
    }
}

__global__ __launch_bounds__(256) void gather_kernel(
    const float4* __restrict__ cost4, uint32_t* __restrict__ meta,
    uint32_t* __restrict__ candv, uint32_t* __restrict__ candi,
    int n4, int f4pb) {
    __shared__ uint32_t l_cv[LCAP];
    __shared__ uint32_t l_ci[LCAP];
    __shared__ uint32_t l_cnt, l_base;
    const int b = blockIdx.y;
    const uint32_t lo = meta[b * 16 + 0];
    const uint32_t hi = meta[b * 16 + 1];
    if (threadIdx.x == 0) l_cnt = 0;
    __syncthreads();
    const size_t base = (size_t)b * n4 + (size_t)blockIdx.x * f4pb;
    const uint32_t elem0 = (uint32_t)blockIdx.x * f4pb * 4u;
    const int iters = f4pb / 256;
    for (int it = 0; it < iters; ++it) {
        float4 v = cost4[base + it * 256 + threadIdx.x];
        const uint32_t e0 = elem0 + (uint32_t)(it * 256 + threadIdx.x) * 4u;
        const float x[4] = {v.x, v.y, v.z, v.w};
        #pragma unroll
        for (int j = 0; j < 4; ++j) {
            const uint32_t bi = costBin(x[j]);
            if (bi >= lo && bi <= hi) {
                const uint32_t p = atomicAdd(&l_cnt, 1u);
                if (p < (uint32_t)LCAP) {
                    l_cv[p] = __float_as_uint(x[j]);
                    l_ci[p] = e0 + (uint32_t)j;
                }
            }
        }
    }
    __syncthreads();
    const uint32_t n = (l_cnt > (uint32_t)LCAP) ? (uint32_t)LCAP : l_cnt;
    if (threadIdx.x == 0) l_base = atomicAdd(&meta[b * 16 + 4], n);
    __syncthreads();
    uint32_t* cv = candv + (size_t)b * CAP;
    uint32_t* ci = candi + (size_t)b * CAP;
    const uint32_t gb = l_base;
    for (uint32_t i = threadIdx.x; i < n; i += 256) {
        const uint32_t g = gb + i;
        if (g < (uint32_t)CAP) { cv[g] = l_cv[i]; ci[g] = l_ci[i]; }
    }
}

// One block per batch: exact importance-bit threshold + tie-break index.
__global__ __launch_bounds__(256) void solve_kernel(
    uint32_t* __restrict__ meta, const uint32_t* __restrict__ candv,
    const uint32_t* __restrict__ candi, uint32_t K, int N) {
    const int b = blockIdx.x;
    uint32_t* mb = meta + b * 16;
    const uint32_t cnt0 = mb[4];
    const uint32_t cnt = (cnt0 > (uint32_t)CAP) ? (uint32_t)CAP : cnt0;
    const uint32_t base = mb[3];
    const uint32_t need = K - base;  // rank of c_(K) among candidates
    const uint32_t* cv = candv + (size_t)b * CAP;
    const uint32_t* ci = candi + (size_t)b * CAP;
    __shared__ uint32_t scv[LDSCV];
    __shared__ uint32_t s[256];
    const int t = threadIdx.x;
    for (uint32_t j = t; j < cnt; j += 256)
        if (j < (uint32_t)LDSCV) scv[j] = cv[j];
    __syncthreads();

    // 1) binary search over cost bits (bounded by candidate bin range):
    //    smallest v with count(cbits <= v) >= need  ->  v = bits(c_(K))
    const uint32_t lobin = mb[0], hibin = mb[1];
    uint32_t lo = __float_as_uint((float)lobin / (float)HBINS);
    uint32_t hi = __float_as_uint((float)(hibin + 1) / (float)HBINS);
    lo = (lo > 64u) ? lo - 64u : 0u;   // slack for bin-edge rounding
    hi += 64u;
    while (lo < hi) {
        const uint32_t mid = lo + ((hi - lo) >> 1);
        uint32_t c = 0;
        for (uint32_t j = t; j < cnt; j += 256) {
            const uint32_t v = (j < (uint32_t)LDSCV) ? scv[j] : cv[j];
            c += (v <= mid) ? 1u : 0u;
        }
        s[t] = c;
        __syncthreads();
        for (int st = 128; st > 0; st >>= 1) {
            if (t < st) s[t] += s[t + st];
            __syncthreads();
        }
        const uint32_t tot = s[0];
        __syncthreads();
        if (tot >= need) hi = mid; else lo = mid + 1;
    }
    const uint32_t thr = impBits(__uint_as_float(lo));

    // 2) count imp > thr and imp == thr among candidates
    uint32_t cg = 0, ce = 0;
    for (uint32_t j = t; j < cnt; j += 256) {
        const uint32_t v = (j < (uint32_t)LDSCV) ? scv[j] : cv[j];
        const uint32_t ib = impBits(__uint_as_float(v));
        cg += (ib > thr) ? 1u : 0u;
        ce += (ib == thr) ? 1u : 0u;
    }
    s[t] = cg;
    __syncthreads();
    for (int st = 128; st > 0; st >>= 1) {
        if (t < st) s[t] += s[t + st];
        __syncthreads();
    }
    const uint32_t gt = s[0];
    __syncthreads();
    s[t] = ce;
    __syncthreads();
    for (int st = 128; st > 0; st >>= 1) {
        if (t < st) s[t] += s[t + st];
        __syncthreads();
    }
    const uint32_t eq = s[0];
    __syncthreads();

    const uint32_t m = need - gt;  // # threshold-equal elements to take
    uint32_t idxthr = 0xFFFFFFFFu;
    if (m < eq) {
        // 3) m-th smallest flat index among equals
        uint32_t l2 = 0u, h2 = (uint32_t)N - 1u;
        while (l2 < h2) {
            const uint32_t mid = (l2 + h2) >> 1;
            uint32_t c = 0;
            for (uint32_t j = t; j < cnt; j += 256) {
                const uint32_t v = (j < (uint32_t)LDSCV) ? scv[j] : cv[j];
                c += (impBits(__uint_as_float(v)) == thr && ci[j] <= mid) ? 1u : 0u;
            }
            s[t] = c;
            __syncthreads();
            for (int st = 128; st > 0; st >>= 1) {
                if (t < st) s[t] += s[t + st];
                __syncthreads();
            }
            const uint32_t tot = s[0];
            __syncthreads();
            if (tot >= m) h2 = mid; else l2 = mid + 1;
        }
        idxthr = l2;
    }
    if (t == 0) { mb[2] = thr; mb[5] = idxthr; }
}

__global__ __launch_bounds__(256) void final_kernel(
    const float4* __restrict__ cost4, float4* __restrict__ out4,
    const uint32_t* __restrict__ meta, int n4) {
    const int b = blockIdx.y;
    const uint32_t t = meta[b * 16 + 2];
    const uint32_t idxthr = meta[b * 16 + 5];
    const int idx = blockIdx.x * 256 + threadIdx.x;
    const size_t off = (size_t)b * n4 + idx;
    float4 v = cost4[off];
    const uint32_t base = (uint32_t)idx * 4u;
    float4 r;
    uint32_t bx;
    bx = impBits(v.x); r.x = (bx > t || (bx == t && base + 0 <= idxthr)) ? v.x : 0.0f;
    bx = impBits(v.y); r.y = (bx > t || (bx == t && base + 1 <= idxthr)) ? v.y : 0.0f;
    bx = impBits(v.z); r.z = (bx > t || (bx == t && base + 2 <= idxthr)) ? v.z : 0.0f;
    bx = impBits(v.w); r.w = (bx > t || (bx == t && base + 3 <= idxthr)) ? v.w : 0.0f;
    out4[off] = r;
}

extern "C" void kernel_launch(void* const* d_in, const int* in_sizes, int n_in,
                              void* d_out, int out_size, void* d_ws, size_t ws_size,
                              hipStream_t stream) {
    const float* src  = (const float*)d_in[0];
    const float* tgt  = (const float*)d_in[1];
    const float* cost = (const float*)d_in[2];
    const int srcN = in_sizes[0];
    const int tgtN = in_sizes[1];
    const int costN = in_sizes[2];
    const int S = 1024, T = 1024;
    const int N = S * T;
    const int B = costN / N;
    const uint32_t K = (uint32_t)(((uint64_t)N * 2ull) / 10ull);  // int(N*0.2)

    float* out = (float*)d_out;
    hipMemcpyAsync(out, src, sizeof(float) * (size_t)srcN,
                   hipMemcpyDeviceToDevice, stream);
    hipMemcpyAsync(out + srcN, tgt, sizeof(float) * (size_t)tgtN,
                   hipMemcpyDeviceToDevice, stream);
    float* outCost = out + (size_t)srcN + tgtN;

    uint32_t* hist  = (uint32_t*)d_ws;
    uint32_t* meta  = hist + (size_t)B * HBINS;
    uint32_t* candv = meta + (size_t)B * 16;
    uint32_t* candi = candv + (size_t)B * CAP;
    const size_t zeroBytes = sizeof(uint32_t) * ((size_t)B * (HBINS + 16));
    hipMemsetAsync(d_ws, 0, zeroBytes, stream);

    const int n4 = N / 4;               // 262144
    const int BPB = 64;                 // fat blocks per batch
    const int f4pb = n4 / BPB;          // 4096 float4 per block

    dim3 fat(BPB, B, 1);
    dim3 thin(n4 / 256, B, 1);
    dim3 blk(256, 1, 1);

    histc_kernel<<<fat, blk, 0, stream>>>((const float4*)cost, hist, n4, f4pb);
    scan_kernel<<<B, 256, 0, stream>>>(hist, meta, K);
    gather_kernel<<<fat, blk, 0, stream>>>((const float4*)cost, meta, candv, candi, n4, f4pb);
    solve_kernel<<<B, 256, 0, stream>>>(meta, candv, candi, K, N);
    final_kernel<<<thin, blk, 0, stream>>>((const float4*)cost, (float4*)outCost, meta, n4);
}

// Round 5
// 116.842 us; speedup vs baseline: 2.8038x; 1.5197x over previous
//
#include <hip/hip_runtime.h>
#include <stdint.h>

// ImportanceSparsification: per-batch top-k (k = 0.2*S*T) of 1/(cost+1e-8),
// out = (source, target, cost*mask). Exact selection with jax top_k
// tie-break (lowest flat index among equal importance values).
//
// R4 -> R5:
//  - solve_kernel was 120us: ~80 LDS-tree block reductions (10 barriers each,
//    dependent LDS round-trips). Rewritten with shfl_xor wave butterflies
//    (2 barriers/round), min/max-narrowed bsearch range, m==1 tie fast path.
//  - gather read-pass fused into hist kernel via speculative window
//    (0.2-quantile of uniform lands in bins [101,103] of 512; spec window
//    [100,105]); scan validates, fallback gather (normally no-op) is exact.
//  - src/tgt copies fused into final kernel (one 1D grid over whole output).

static constexpr int HBINS = 512;     // linear cost bins
static constexpr int CAP   = 32768;   // per-batch candidate cap (global)
static constexpr int LCAP  = 1024;    // per-block candidate staging (LDS)
static constexpr int LDSCV = 14336;   // solve: LDS-staged candidate values
static constexpr uint32_t SPEC_LO = 100;  // speculative gather window (bins)
static constexpr uint32_t SPEC_HI = 105;
static constexpr float EPSF = 1e-8f;

__device__ __forceinline__ uint32_t impBits(float c) {
    // IEEE-correct f32 ops (no fast-math) -> bit-exact vs numpy reference
    return __float_as_uint(1.0f / (c + EPSF));
}

__device__ __forceinline__ uint32_t costBin(float x) {
    uint32_t bi = (uint32_t)(x * (float)HBINS);  // x in [0,1)
    return bi > (HBINS - 1) ? (HBINS - 1) : bi;
}

// meta per batch (16 u32):
// [0]=lo_bin [1]=hi_bin [2]=t [3]=base [4]=candcnt [5]=idxthr [7]=spec_ok

// ---- pass 1: histogram + speculative candidate gather (one read pass) ----
__global__ __launch_bounds__(256) void histgather_kernel(
    const float4* __restrict__ cost4, uint32_t* __restrict__ hist,
    uint32_t* __restrict__ meta, uint32_t* __restrict__ candv,
    uint32_t* __restrict__ candi, int n4, int f4pb) {
    __shared__ uint32_t lh[HBINS];
    __shared__ uint32_t l_cv[LCAP];
    __shared__ uint32_t l_ci[LCAP];
    __shared__ uint32_t l_cnt, l_base;
    const int b = blockIdx.y;
    for (int i = threadIdx.x; i < HBINS; i += 256) lh[i] = 0;
    if (threadIdx.x == 0) l_cnt = 0;
    __syncthreads();
    const size_t base = (size_t)b * n4 + (size_t)blockIdx.x * f4pb;
    const uint32_t elem0 = (uint32_t)blockIdx.x * f4pb * 4u;
    const int iters = f4pb / 256;
    for (int it = 0; it < iters; ++it) {
        float4 v = cost4[base + it * 256 + threadIdx.x];
        const uint32_t e0 = elem0 + (uint32_t)(it * 256 + threadIdx.x) * 4u;
        const float x[4] = {v.x, v.y, v.z, v.w};
        #pragma unroll
        for (int j = 0; j < 4; ++j) {
            const uint32_t bi = costBin(x[j]);
            atomicAdd(&lh[bi], 1u);
            if (bi >= SPEC_LO && bi <= SPEC_HI) {
                const uint32_t p = atomicAdd(&l_cnt, 1u);
                if (p < (uint32_t)LCAP) {
                    l_cv[p] = __float_as_uint(x[j]);
                    l_ci[p] = e0 + (uint32_t)j;
                }
            }
        }
    }
    __syncthreads();
    uint32_t* gh = hist + (size_t)b * HBINS;
    for (int i = threadIdx.x; i < HBINS; i += 256)
        if (lh[i]) atomicAdd(&gh[i], lh[i]);
    const uint32_t n = (l_cnt > (uint32_t)LCAP) ? (uint32_t)LCAP : l_cnt;
    if (threadIdx.x == 0) l_base = atomicAdd(&meta[b * 16 + 4], n);
    __syncthreads();
    uint32_t* cv = candv + (size_t)b * CAP;
    uint32_t* ci = candi + (size_t)b * CAP;
    const uint32_t gb = l_base;
    for (uint32_t i = threadIdx.x; i < n; i += 256) {
        const uint32_t g = gb + i;
        if (g < (uint32_t)CAP) { cv[g] = l_cv[i]; ci[g] = l_ci[i]; }
    }
}

// ---- pass 2: prefix-scan 512 bins, locate K-th-smallest bin, validate ----
__global__ __launch_bounds__(256) void scan_kernel(
    const uint32_t* __restrict__ hist, uint32_t* __restrict__ meta, uint32_t K) {
    const int b = blockIdx.x;
    const uint32_t* h = hist + (size_t)b * HBINS;
    __shared__ uint32_t s[256];
    const int t = threadIdx.x;
    const int C = HBINS / 256;  // 2 bins per thread
    uint32_t hv[C];
    uint32_t csum = 0;
    for (int i = 0; i < C; ++i) { hv[i] = h[t * C + i]; csum += hv[i]; }
    s[t] = csum;
    __syncthreads();
    for (int off = 1; off < 256; off <<= 1) {
        uint32_t add = (t >= off) ? s[t - off] : 0u;
        uint32_t cur = s[t];
        __syncthreads();
        s[t] = cur + add;
        __syncthreads();
    }
    const uint32_t before = s[t] - csum;
    if (before < K && s[t] >= K) {
        uint32_t cum = before;
        for (int i = 0; i < C; ++i) {
            const uint32_t c = hv[i];
            if (cum + c >= K) {
                const uint32_t q = (uint32_t)(t * C + i);
                if (q >= SPEC_LO && q <= SPEC_HI) {
                    // speculation hit: window = [SPEC_LO, SPEC_HI],
                    // base = prefix(SPEC_LO-1) = bins 0..99 = chunks 0..49
                    meta[b * 16 + 0] = SPEC_LO;
                    meta[b * 16 + 1] = SPEC_HI;
                    meta[b * 16 + 3] = s[(SPEC_LO / C) - 1];
                    meta[b * 16 + 7] = 1u;
                } else {
                    // miss: discard speculative candidates, fallback window
                    const uint32_t lo = (q > 0) ? q - 1 : 0;
                    const uint32_t hi = (q < HBINS - 1) ? q + 1 : (HBINS - 1);
                    meta[b * 16 + 0] = lo;
                    meta[b * 16 + 1] = hi;
                    meta[b * 16 + 3] = cum - ((q > 0) ? h[q - 1] : 0u);
                    meta[b * 16 + 4] = 0u;
                    meta[b * 16 + 7] = 0u;
                }
                break;
            }
            cum += c;
        }
    }
}

// ---- pass 3 (normally no-op): exact gather when speculation missed ----
__global__ __launch_bounds__(256) void fallback_gather_kernel(
    const float4* __restrict__ cost4, uint32_t* __restrict__ meta,
    uint32_t* __restrict__ candv, uint32_t* __restrict__ candi,
    int n4, int f4pb) {
    const int b = blockIdx.y;
    if (meta[b * 16 + 7]) return;  // speculation hit
    __shared__ uint32_t l_cv[LCAP];
    __shared__ uint32_t l_ci[LCAP];
    __shared__ uint32_t l_cnt, l_base;
    const uint32_t lo = meta[b * 16 + 0];
    const uint32_t hi = meta[b * 16 + 1];
    if (threadIdx.x == 0) l_cnt = 0;
    __syncthreads();
    const size_t base = (size_t)b * n4 + (size_t)blockIdx.x * f4pb;
    const uint32_t elem0 = (uint32_t)blockIdx.x * f4pb * 4u;
    const int iters = f4pb / 256;
    for (int it = 0; it < iters; ++it) {
        float4 v = cost4[base + it * 256 + threadIdx.x];
        const uint32_t e0 = elem0 + (uint32_t)(it * 256 + threadIdx.x) * 4u;
        const float x[4] = {v.x, v.y, v.z, v.w};
        #pragma unroll
        for (int j = 0; j < 4; ++j) {
            const uint32_t bi = costBin(x[j]);
            if (bi >= lo && bi <= hi) {
                const uint32_t p = atomicAdd(&l_cnt, 1u);
                if (p < (uint32_t)LCAP) {
                    l_cv[p] = __float_as_uint(x[j]);
                    l_ci[p] = e0 + (uint32_t)j;
                }
            }
        }
    }
    __syncthreads();
    const uint32_t n = (l_cnt > (uint32_t)LCAP) ? (uint32_t)LCAP : l_cnt;
    if (threadIdx.x == 0) l_base = atomicAdd(&meta[b * 16 + 4], n);
    __syncthreads();
    uint32_t* cv = candv + (size_t)b * CAP;
    uint32_t* ci = candi + (size_t)b * CAP;
    const uint32_t gb = l_base;
    for (uint32_t i = threadIdx.x; i < n; i += 256) {
        const uint32_t g = gb + i;
        if (g < (uint32_t)CAP) { cv[g] = l_cv[i]; ci[g] = l_ci[i]; }
    }
}

// ---- pass 4: exact threshold + tie index; shfl-based reductions ----
__global__ __launch_bounds__(256) void solve_kernel(
    uint32_t* __restrict__ meta, const uint32_t* __restrict__ candv,
    const uint32_t* __restrict__ candi, uint32_t K, int N) {
    const int b = blockIdx.x;
    uint32_t* mb = meta + b * 16;
    const uint32_t cnt0 = mb[4];
    const uint32_t cnt = (cnt0 > (uint32_t)CAP) ? (uint32_t)CAP : cnt0;
    const uint32_t need = K - mb[3];  // rank of c_(K) among candidates
    const uint32_t* cv = candv + (size_t)b * CAP;
    const uint32_t* ci = candi + (size_t)b * CAP;
    __shared__ uint32_t scv[LDSCV];
    __shared__ uint32_t sw[16];
    const int t = threadIdx.x;
    const int w = t >> 6, ln = t & 63;

    // stage candidates in LDS; block min/max of cost bits
    uint32_t mn = 0xFFFFFFFFu, mx = 0u;
    for (uint32_t j = t; j < cnt; j += 256) {
        const uint32_t v = cv[j];
        if (j < (uint32_t)LDSCV) scv[j] = v;
        mn = (v < mn) ? v : mn;
        mx = (v > mx) ? v : mx;
    }
    #pragma unroll
    for (int o = 1; o < 64; o <<= 1) {
        const uint32_t a = (uint32_t)__shfl_xor((int)mn, o);
        const uint32_t z = (uint32_t)__shfl_xor((int)mx, o);
        mn = (a < mn) ? a : mn;
        mx = (z > mx) ? z : mx;
    }
    if (ln == 0) { sw[w] = mn; sw[4 + w] = mx; }
    __syncthreads();
    uint32_t lo = sw[0], hi = sw[4];
    #pragma unroll
    for (int i = 1; i < 4; ++i) {
        lo = (sw[i] < lo) ? sw[i] : lo;
        hi = (sw[4 + i] > hi) ? sw[4 + i] : hi;
    }
    __syncthreads();

    // bsearch: smallest v in [lo,hi] with count(cbits <= v) >= need
    while (lo < hi) {
        const uint32_t mid = lo + ((hi - lo) >> 1);
        uint32_t c = 0;
        for (uint32_t j = t; j < cnt; j += 256)
            c += ((j < (uint32_t)LDSCV ? scv[j] : cv[j]) <= mid) ? 1u : 0u;
        #pragma unroll
        for (int o = 1; o < 64; o <<= 1) c += (uint32_t)__shfl_xor((int)c, o);
        if (ln == 0) sw[w] = c;
        __syncthreads();
        const uint32_t tot = sw[0] + sw[1] + sw[2] + sw[3];
        __syncthreads();
        if (tot >= need) hi = mid; else lo = mid + 1;
    }
    const uint32_t thr = impBits(__uint_as_float(lo));

    // count gt/eq; min/max index among equals
    uint32_t cg = 0, ce = 0, imn = 0xFFFFFFFFu, imx = 0u;
    for (uint32_t j = t; j < cnt; j += 256) {
        const uint32_t v = (j < (uint32_t)LDSCV) ? scv[j] : cv[j];
        const uint32_t ib = impBits(__uint_as_float(v));
        cg += (ib > thr) ? 1u : 0u;
        if (ib == thr) {
            ce++;
            const uint32_t ix = ci[j];
            imn = (ix < imn) ? ix : imn;
            imx = (ix > imx) ? ix : imx;
        }
    }
    #pragma unroll
    for (int o = 1; o < 64; o <<= 1) {
        cg += (uint32_t)__shfl_xor((int)cg, o);
        ce += (uint32_t)__shfl_xor((int)ce, o);
        const uint32_t a = (uint32_t)__shfl_xor((int)imn, o);
        const uint32_t z = (uint32_t)__shfl_xor((int)imx, o);
        imn = (a < imn) ? a : imn;
        imx = (z > imx) ? z : imx;
    }
    if (ln == 0) { sw[w] = cg; sw[4 + w] = ce; sw[8 + w] = imn; sw[12 + w] = imx; }
    __syncthreads();
    uint32_t gt = 0, eq = 0, imin = 0xFFFFFFFFu, imax = 0u;
    #pragma unroll
    for (int i = 0; i < 4; ++i) {
        gt += sw[i];
        eq += sw[4 + i];
        imin = (sw[8 + i] < imin) ? sw[8 + i] : imin;
        imax = (sw[12 + i] > imax) ? sw[12 + i] : imax;
    }
    __syncthreads();

    const uint32_t m = need - gt;  // # threshold-equal elements to take (>=1)
    uint32_t idxthr = 0xFFFFFFFFu;
    if (m < eq) {
        if (m == 1) {
            idxthr = imin;
        } else {
            // m-th smallest flat index among equals, bsearch in [imin, imax]
            uint32_t l2 = imin, h2 = imax;
            while (l2 < h2) {
                const uint32_t mid = l2 + ((h2 - l2) >> 1);
                uint32_t c = 0;
                for (uint32_t j = t; j < cnt; j += 256) {
                    const uint32_t v = (j < (uint32_t)LDSCV) ? scv[j] : cv[j];
                    c += (impBits(__uint_as_float(v)) == thr && ci[j] <= mid) ? 1u : 0u;
                }
                #pragma unroll
                for (int o = 1; o < 64; o <<= 1) c += (uint32_t)__shfl_xor((int)c, o);
                if (ln == 0) sw[w] = c;
                __syncthreads();
                const uint32_t tot = sw[0] + sw[1] + sw[2] + sw[3];
                __syncthreads();
                if (tot >= m) h2 = mid; else l2 = mid + 1;
            }
            idxthr = l2;
        }
    }
    if (t == 0) { mb[2] = thr; mb[5] = idxthr; }
}

// ---- pass 5: fused output (src copy | tgt copy | masked cost) ----
__global__ __launch_bounds__(256) void final_kernel(
    const float4* __restrict__ src4, const float4* __restrict__ tgt4,
    const float4* __restrict__ cost4, float4* __restrict__ out4,
    const uint32_t* __restrict__ meta, int s4, int t4, int l2n4) {
    const int idx = blockIdx.x * 256 + threadIdx.x;
    if (idx < s4) { out4[idx] = src4[idx]; return; }
    int r = idx - s4;
    if (r < t4) { out4[idx] = tgt4[r]; return; }
    r -= t4;
    const int b = r >> l2n4;
    const uint32_t t = meta[b * 16 + 2];
    const uint32_t idxthr = meta[b * 16 + 5];
    const int i = r & ((1 << l2n4) - 1);
    float4 v = cost4[(size_t)b * (1 << l2n4) + i];
    const uint32_t base = (uint32_t)i * 4u;
    float4 o;
    uint32_t bx;
    bx = impBits(v.x); o.x = (bx > t || (bx == t && base + 0 <= idxthr)) ? v.x : 0.0f;
    bx = impBits(v.y); o.y = (bx > t || (bx == t && base + 1 <= idxthr)) ? v.y : 0.0f;
    bx = impBits(v.z); o.z = (bx > t || (bx == t && base + 2 <= idxthr)) ? v.z : 0.0f;
    bx = impBits(v.w); o.w = (bx > t || (bx == t && base + 3 <= idxthr)) ? v.w : 0.0f;
    out4[idx] = o;
}

extern "C" void kernel_launch(void* const* d_in, const int* in_sizes, int n_in,
                              void* d_out, int out_size, void* d_ws, size_t ws_size,
                              hipStream_t stream) {
    const float* src  = (const float*)d_in[0];
    const float* tgt  = (const float*)d_in[1];
    const float* cost = (const float*)d_in[2];
    const int srcN = in_sizes[0];
    const int tgtN = in_sizes[1];
    const int costN = in_sizes[2];
    const int S = 1024, T = 1024;
    const int N = S * T;
    const int B = costN / N;
    const uint32_t K = (uint32_t)(((uint64_t)N * 2ull) / 10ull);  // int(N*0.2)

    float* out = (float*)d_out;

    uint32_t* hist  = (uint32_t*)d_ws;
    uint32_t* meta  = hist + (size_t)B * HBINS;
    uint32_t* candv = meta + (size_t)B * 16;
    uint32_t* candi = candv + (size_t)B * CAP;
    const size_t zeroBytes = sizeof(uint32_t) * ((size_t)B * (HBINS + 16));
    hipMemsetAsync(d_ws, 0, zeroBytes, stream);

    const int n4 = N / 4;               // 262144 = 2^18
    const int BPB = 64;                 // fat blocks per batch
    const int f4pb = n4 / BPB;          // 4096 float4 per block
    int l2n4 = 0;
    while ((1 << l2n4) < n4) ++l2n4;

    dim3 fat(BPB, B, 1);
    dim3 blk(256, 1, 1);

    histgather_kernel<<<fat, blk, 0, stream>>>(
        (const float4*)cost, hist, meta, candv, candi, n4, f4pb);
    scan_kernel<<<B, 256, 0, stream>>>(hist, meta, K);
    fallback_gather_kernel<<<fat, blk, 0, stream>>>(
        (const float4*)cost, meta, candv, candi, n4, f4pb);
    solve_kernel<<<B, 256, 0, stream>>>(meta, candv, candi, K, N);

    const int s4 = srcN / 4, t4 = tgtN / 4;
    const int total4 = s4 + t4 + B * n4;
    final_kernel<<<(total4 + 255) / 256, blk, 0, stream>>>(
        (const float4*)src, (const float4*)tgt, (const float4*)cost,
        (float4*)out, meta, s4, t4, l2n4);
}

// Round 6
// 69.463 us; speedup vs baseline: 4.7162x; 1.6821x over previous
//
#include <hip/hip_runtime.h>
#include <stdint.h>

// ImportanceSparsification: per-batch top-k (k = 0.2*S*T) of 1/(cost+1e-8),
// out = (source, target, cost*mask). Exact selection with jax top_k
// tie-break (lowest flat index among equal importance values).
//
// R5 -> R6: solve_kernel was 64us (latency-bound: ~40 barrier rounds of
// bsearch, 48 LDS reads/thread each). Replaced bit-range bsearch with
// 2-level histogram-descent (2048 bins/level, 2 barriers/level) and the
// index bsearch with O(eq) LDS rank-select (m==1 -> min-index reduce).
// 512 threads/block. Spec window tightened to [100,104], accept q in
// [101,103] so the equal-importance plateau stays strictly inside the
// window (exactness). Expected solve ~5us.

static constexpr int HBINS = 512;     // linear cost bins
static constexpr int CAP   = 32768;   // per-batch candidate cap (global)
static constexpr int LCAP  = 1024;    // per-block candidate staging (LDS)
static constexpr int LDSCV = 12288;   // solve: LDS-staged candidate values
static constexpr int TIECAP = 2048;   // solve: LDS tie-index list cap
static constexpr int NT    = 512;     // solve block size
static constexpr int NW    = NT / 64; // waves in solve block
static constexpr uint32_t SPEC_LO = 100;  // speculative gather window (bins)
static constexpr uint32_t SPEC_HI = 104;
static constexpr float EPSF = 1e-8f;

__device__ __forceinline__ uint32_t impBits(float c) {
    // IEEE-correct f32 ops (no fast-math) -> bit-exact vs numpy reference
    return __float_as_uint(1.0f / (c + EPSF));
}

__device__ __forceinline__ uint32_t costBin(float x) {
    uint32_t bi = (uint32_t)(x * (float)HBINS);  // x in [0,1)
    return bi > (HBINS - 1) ? (HBINS - 1) : bi;
}

// meta per batch (16 u32):
// [0]=lo_bin [1]=hi_bin [2]=t [3]=base [4]=candcnt [5]=idxthr [7]=spec_ok

// ---- pass 1: histogram + speculative candidate gather (one read pass) ----
__global__ __launch_bounds__(256) void histgather_kernel(
    const float4* __restrict__ cost4, uint32_t* __restrict__ hist,
    uint32_t* __restrict__ meta, uint32_t* __restrict__ candv,
    uint32_t* __restrict__ candi, int n4, int f4pb) {
    __shared__ uint32_t lh[HBINS];
    __shared__ uint32_t l_cv[LCAP];
    __shared__ uint32_t l_ci[LCAP];
    __shared__ uint32_t l_cnt, l_base;
    const int b = blockIdx.y;
    for (int i = threadIdx.x; i < HBINS; i += 256) lh[i] = 0;
    if (threadIdx.x == 0) l_cnt = 0;
    __syncthreads();
    const size_t base = (size_t)b * n4 + (size_t)blockIdx.x * f4pb;
    const uint32_t elem0 = (uint32_t)blockIdx.x * f4pb * 4u;
    const int iters = f4pb / 256;
    for (int it = 0; it < iters; ++it) {
        float4 v = cost4[base + it * 256 + threadIdx.x];
        const uint32_t e0 = elem0 + (uint32_t)(it * 256 + threadIdx.x) * 4u;
        const float x[4] = {v.x, v.y, v.z, v.w};
        #pragma unroll
        for (int j = 0; j < 4; ++j) {
            const uint32_t bi = costBin(x[j]);
            atomicAdd(&lh[bi], 1u);
            if (bi >= SPEC_LO && bi <= SPEC_HI) {
                const uint32_t p = atomicAdd(&l_cnt, 1u);
                if (p < (uint32_t)LCAP) {
                    l_cv[p] = __float_as_uint(x[j]);
                    l_ci[p] = e0 + (uint32_t)j;
                }
            }
        }
    }
    __syncthreads();
    uint32_t* gh = hist + (size_t)b * HBINS;
    for (int i = threadIdx.x; i < HBINS; i += 256)
        if (lh[i]) atomicAdd(&gh[i], lh[i]);
    const uint32_t n = (l_cnt > (uint32_t)LCAP) ? (uint32_t)LCAP : l_cnt;
    if (threadIdx.x == 0) l_base = atomicAdd(&meta[b * 16 + 4], n);
    __syncthreads();
    uint32_t* cv = candv + (size_t)b * CAP;
    uint32_t* ci = candi + (size_t)b * CAP;
    const uint32_t gb = l_base;
    for (uint32_t i = threadIdx.x; i < n; i += 256) {
        const uint32_t g = gb + i;
        if (g < (uint32_t)CAP) { cv[g] = l_cv[i]; ci[g] = l_ci[i]; }
    }
}

// ---- pass 2: prefix-scan 512 bins, locate K-th-smallest bin, validate ----
__global__ __launch_bounds__(256) void scan_kernel(
    const uint32_t* __restrict__ hist, uint32_t* __restrict__ meta, uint32_t K) {
    const int b = blockIdx.x;
    const uint32_t* h = hist + (size_t)b * HBINS;
    __shared__ uint32_t s[256];
    const int t = threadIdx.x;
    const int C = HBINS / 256;  // 2 bins per thread
    uint32_t hv[C];
    uint32_t csum = 0;
    for (int i = 0; i < C; ++i) { hv[i] = h[t * C + i]; csum += hv[i]; }
    s[t] = csum;
    __syncthreads();
    for (int off = 1; off < 256; off <<= 1) {
        uint32_t add = (t >= off) ? s[t - off] : 0u;
        uint32_t cur = s[t];
        __syncthreads();
        s[t] = cur + add;
        __syncthreads();
    }
    const uint32_t before = s[t] - csum;
    if (before < K && s[t] >= K) {
        uint32_t cum = before;
        for (int i = 0; i < C; ++i) {
            const uint32_t c = hv[i];
            if (cum + c >= K) {
                const uint32_t q = (uint32_t)(t * C + i);
                // accept only interior bins so the equal-importance plateau
                // (few ulps wide) cannot escape the gathered window
                if (q > SPEC_LO && q < SPEC_HI) {
                    meta[b * 16 + 0] = SPEC_LO;
                    meta[b * 16 + 1] = SPEC_HI;
                    meta[b * 16 + 3] = s[(SPEC_LO / C) - 1];  // bins < SPEC_LO
                    meta[b * 16 + 7] = 1u;
                } else {
                    const uint32_t lo = (q > 0) ? q - 1 : 0;
                    const uint32_t hi = (q < HBINS - 1) ? q + 1 : (HBINS - 1);
                    meta[b * 16 + 0] = lo;
                    meta[b * 16 + 1] = hi;
                    meta[b * 16 + 3] = cum - ((q > 0) ? h[q - 1] : 0u);
                    meta[b * 16 + 4] = 0u;
                    meta[b * 16 + 7] = 0u;
                }
                break;
            }
            cum += c;
        }
    }
}

// ---- pass 3 (normally no-op): exact gather when speculation missed ----
__global__ __launch_bounds__(256) void fallback_gather_kernel(
    const float4* __restrict__ cost4, uint32_t* __restrict__ meta,
    uint32_t* __restrict__ candv, uint32_t* __restrict__ candi,
    int n4, int f4pb) {
    const int b = blockIdx.y;
    if (meta[b * 16 + 7]) return;  // speculation hit
    __shared__ uint32_t l_cv[LCAP];
    __shared__ uint32_t l_ci[LCAP];
    __shared__ uint32_t l_cnt, l_base;
    const uint32_t lo = meta[b * 16 + 0];
    const uint32_t hi = meta[b * 16 + 1];
    if (threadIdx.x == 0) l_cnt = 0;
    __syncthreads();
    const size_t base = (size_t)b * n4 + (size_t)blockIdx.x * f4pb;
    const uint32_t elem0 = (uint32_t)blockIdx.x * f4pb * 4u;
    const int iters = f4pb / 256;
    for (int it = 0; it < iters; ++it) {
        float4 v = cost4[base + it * 256 + threadIdx.x];
        const uint32_t e0 = elem0 + (uint32_t)(it * 256 + threadIdx.x) * 4u;
        const float x[4] = {v.x, v.y, v.z, v.w};
        #pragma unroll
        for (int j = 0; j < 4; ++j) {
            const uint32_t bi = costBin(x[j]);
            if (bi >= lo && bi <= hi) {
                const uint32_t p = atomicAdd(&l_cnt, 1u);
                if (p < (uint32_t)LCAP) {
                    l_cv[p] = __float_as_uint(x[j]);
                    l_ci[p] = e0 + (uint32_t)j;
                }
            }
        }
    }
    __syncthreads();
    const uint32_t n = (l_cnt > (uint32_t)LCAP) ? (uint32_t)LCAP : l_cnt;
    if (threadIdx.x == 0) l_base = atomicAdd(&meta[b * 16 + 4], n);
    __syncthreads();
    uint32_t* cv = candv + (size_t)b * CAP;
    uint32_t* ci = candi + (size_t)b * CAP;
    const uint32_t gb = l_base;
    for (uint32_t i = threadIdx.x; i < n; i += 256) {
        const uint32_t g = gb + i;
        if (g < (uint32_t)CAP) { cv[g] = l_cv[i]; ci[g] = l_ci[i]; }
    }
}

// ---- pass 4: exact threshold + tie index via histogram descent ----
__global__ __launch_bounds__(NT) void solve_kernel(
    uint32_t* __restrict__ meta, const uint32_t* __restrict__ candv,
    const uint32_t* __restrict__ candi, uint32_t K, int N) {
    const int b = blockIdx.x;
    uint32_t* mb = meta + b * 16;
    const uint32_t cnt0 = mb[4];
    const uint32_t cnt = (cnt0 > (uint32_t)CAP) ? (uint32_t)CAP : cnt0;
    const uint32_t need0 = K - mb[3];  // rank of c_(K) among candidates
    const uint32_t* cv = candv + (size_t)b * CAP;
    const uint32_t* ci = candi + (size_t)b * CAP;
    __shared__ uint32_t scv[LDSCV];
    __shared__ uint32_t h[TIECAP];          // level hist / tie-index list
    __shared__ uint32_t sw[4 * NW];
    __shared__ uint32_t s_lo, s_need, s_range, s_tiecnt, s_res;
    const int t = threadIdx.x;
    const int w = t >> 6, ln = t & 63;

    // stage candidate values in LDS; block min/max of cost bits
    uint32_t mn = 0xFFFFFFFFu, mx = 0u;
    for (uint32_t j = t; j < cnt; j += NT) {
        const uint32_t v = cv[j];
        if (j < (uint32_t)LDSCV) scv[j] = v;
        mn = (v < mn) ? v : mn;
        mx = (v > mx) ? v : mx;
    }
    #pragma unroll
    for (int o = 1; o < 64; o <<= 1) {
        const uint32_t a = (uint32_t)__shfl_xor((int)mn, o);
        const uint32_t z = (uint32_t)__shfl_xor((int)mx, o);
        mn = (a < mn) ? a : mn;
        mx = (z > mx) ? z : mx;
    }
    if (ln == 0) { sw[w] = mn; sw[NW + w] = mx; }
    __syncthreads();
    uint32_t lo = sw[0], hix = sw[NW];
    #pragma unroll
    for (int i = 1; i < NW; ++i) {
        lo = (sw[i] < lo) ? sw[i] : lo;
        hix = (sw[NW + i] > hix) ? sw[NW + i] : hix;
    }
    uint32_t range = hix - lo + 1u;   // cost bits < 0x3F800000 -> no overflow
    uint32_t need = need0;

    // histogram descent: resolve exact need-th smallest cost-bit value
    while (range > 1u) {
        const int bits = 32 - __clz((int)(range - 1u));
        const int shift = (bits > 11) ? (bits - 11) : 0;
        for (int i = t; i < TIECAP; i += NT) h[i] = 0;
        __syncthreads();
        for (uint32_t j = t; j < cnt; j += NT) {
            const uint32_t v = (j < (uint32_t)LDSCV) ? scv[j] : cv[j];
            const uint32_t d = v - lo;
            if (v >= lo && d < range) atomicAdd(&h[d >> shift], 1u);
        }
        __syncthreads();
        // ascending prefix over 2048 bins (4 per thread)
        uint32_t hv[4];
        uint32_t csum = 0;
        #pragma unroll
        for (int i = 0; i < 4; ++i) { hv[i] = h[t * 4 + i]; csum += hv[i]; }
        uint32_t incl = csum;
        #pragma unroll
        for (int o = 1; o < 64; o <<= 1) {
            const uint32_t up = (uint32_t)__shfl_up((int)incl, o);
            if (ln >= o) incl += up;
        }
        if (ln == 63) sw[w] = incl;
        __syncthreads();
        uint32_t wpre = 0;
        for (int i = 0; i < w; ++i) wpre += sw[i];
        const uint32_t before = wpre + incl - csum;
        if (before < need && before + csum >= need) {
            uint32_t cum = before;
            #pragma unroll
            for (int i = 0; i < 4; ++i) {
                if (cum + hv[i] >= need) {
                    const uint32_t q = (uint32_t)(t * 4 + i);
                    const uint32_t off = q << shift;
                    s_lo = lo + off;
                    s_need = need - cum;
                    const uint32_t span = range - off;
                    s_range = (span < (1u << shift)) ? span : (1u << shift);
                    break;
                }
                cum += hv[i];
            }
        }
        __syncthreads();
        lo = s_lo; need = s_need; range = s_range;
        __syncthreads();
    }
    const uint32_t thr = impBits(__uint_as_float(lo));

    // count gt/eq; min/max tie index
    uint32_t cg = 0, ce = 0, imn = 0xFFFFFFFFu, imx = 0u;
    for (uint32_t j = t; j < cnt; j += NT) {
        const uint32_t v = (j < (uint32_t)LDSCV) ? scv[j] : cv[j];
        const uint32_t ib = impBits(__uint_as_float(v));
        if (ib > thr) cg++;
        else if (ib == thr) {
            ce++;
            const uint32_t ix = ci[j];
            imn = (ix < imn) ? ix : imn;
            imx = (ix > imx) ? ix : imx;
        }
    }
    #pragma unroll
    for (int o = 1; o < 64; o <<= 1) {
        cg += (uint32_t)__shfl_xor((int)cg, o);
        ce += (uint32_t)__shfl_xor((int)ce, o);
        const uint32_t a = (uint32_t)__shfl_xor((int)imn, o);
        const uint32_t z = (uint32_t)__shfl_xor((int)imx, o);
        imn = (a < imn) ? a : imn;
        imx = (z > imx) ? z : imx;
    }
    if (ln == 0) { sw[w] = cg; sw[NW + w] = ce; sw[2 * NW + w] = imn; sw[3 * NW + w] = imx; }
    __syncthreads();
    uint32_t gt = 0, eq = 0, imin = 0xFFFFFFFFu, imax = 0u;
    #pragma unroll
    for (int i = 0; i < NW; ++i) {
        gt += sw[i];
        eq += sw[NW + i];
        imin = (sw[2 * NW + i] < imin) ? sw[2 * NW + i] : imin;
        imax = (sw[3 * NW + i] > imax) ? sw[3 * NW + i] : imax;
    }
    __syncthreads();

    const uint32_t m = need0 - gt;  // # threshold-equal elements to take (>=1)
    uint32_t idxthr = 0xFFFFFFFFu;
    if (m < eq) {
        if (m == 1) {
            idxthr = imin;
        } else {
            // gather tie indices into LDS, O(eq) rank-select
            if (t == 0) s_tiecnt = 0;
            __syncthreads();
            for (uint32_t j = t; j < cnt; j += NT) {
                const uint32_t v = (j < (uint32_t)LDSCV) ? scv[j] : cv[j];
                if (impBits(__uint_as_float(v)) == thr) {
                    const uint32_t p = atomicAdd(&s_tiecnt, 1u);
                    if (p < (uint32_t)TIECAP) h[p] = ci[j];
                }
            }
            __syncthreads();
            const uint32_t tc = s_tiecnt;
            if (tc <= (uint32_t)TIECAP) {
                for (uint32_t p = t; p < tc; p += NT) {
                    const uint32_t x = h[p];
                    uint32_t r = 0;
                    for (uint32_t q2 = 0; q2 < tc; ++q2) r += (h[q2] < x) ? 1u : 0u;
                    if (r == m - 1) s_res = x;  // unique (flat indices distinct)
                }
                __syncthreads();
                idxthr = s_res;
            } else {
                // unreachable in practice: bsearch m-th smallest index
                uint32_t l2 = imin, h2 = imax;
                while (l2 < h2) {
                    const uint32_t mid = l2 + ((h2 - l2) >> 1);
                    uint32_t c = 0;
                    for (uint32_t j = t; j < cnt; j += NT) {
                        const uint32_t v = (j < (uint32_t)LDSCV) ? scv[j] : cv[j];
                        c += (impBits(__uint_as_float(v)) == thr && ci[j] <= mid) ? 1u : 0u;
                    }
                    #pragma unroll
                    for (int o = 1; o < 64; o <<= 1) c += (uint32_t)__shfl_xor((int)c, o);
                    if (ln == 0) sw[w] = c;
                    __syncthreads();
                    uint32_t tot = 0;
                    for (int i = 0; i < NW; ++i) tot += sw[i];
                    __syncthreads();
                    if (tot >= m) h2 = mid; else l2 = mid + 1;
                }
                idxthr = l2;
            }
        }
    }
    if (t == 0) { mb[2] = thr; mb[5] = idxthr; }
}

// ---- pass 5: fused output (src copy | tgt copy | masked cost) ----
__global__ __launch_bounds__(256) void final_kernel(
    const float4* __restrict__ src4, const float4* __restrict__ tgt4,
    const float4* __restrict__ cost4, float4* __restrict__ out4,
    const uint32_t* __restrict__ meta, int s4, int t4, int l2n4) {
    const int idx = blockIdx.x * 256 + threadIdx.x;
    if (idx < s4) { out4[idx] = src4[idx]; return; }
    int r = idx - s4;
    if (r < t4) { out4[idx] = tgt4[r]; return; }
    r -= t4;
    const int b = r >> l2n4;
    const uint32_t t = meta[b * 16 + 2];
    const uint32_t idxthr = meta[b * 16 + 5];
    const int i = r & ((1 << l2n4) - 1);
    float4 v = cost4[(size_t)b * (1 << l2n4) + i];
    const uint32_t base = (uint32_t)i * 4u;
    float4 o;
    uint32_t bx;
    bx = impBits(v.x); o.x = (bx > t || (bx == t && base + 0 <= idxthr)) ? v.x : 0.0f;
    bx = impBits(v.y); o.y = (bx > t || (bx == t && base + 1 <= idxthr)) ? v.y : 0.0f;
    bx = impBits(v.z); o.z = (bx > t || (bx == t && base + 2 <= idxthr)) ? v.z : 0.0f;
    bx = impBits(v.w); o.w = (bx > t || (bx == t && base + 3 <= idxthr)) ? v.w : 0.0f;
    out4[idx] = o;
}

extern "C" void kernel_launch(void* const* d_in, const int* in_sizes, int n_in,
                              void* d_out, int out_size, void* d_ws, size_t ws_size,
                              hipStream_t stream) {
    const float* src  = (const float*)d_in[0];
    const float* tgt  = (const float*)d_in[1];
    const float* cost = (const float*)d_in[2];
    const int srcN = in_sizes[0];
    const int tgtN = in_sizes[1];
    const int costN = in_sizes[2];
    const int S = 1024, T = 1024;
    const int N = S * T;
    const int B = costN / N;
    const uint32_t K = (uint32_t)(((uint64_t)N * 2ull) / 10ull);  // int(N*0.2)

    float* out = (float*)d_out;

    uint32_t* hist  = (uint32_t*)d_ws;
    uint32_t* meta  = hist + (size_t)B * HBINS;
    uint32_t* candv = meta + (size_t)B * 16;
    uint32_t* candi = candv + (size_t)B * CAP;
    const size_t zeroBytes = sizeof(uint32_t) * ((size_t)B * (HBINS + 16));
    hipMemsetAsync(d_ws, 0, zeroBytes, stream);

    const int n4 = N / 4;               // 262144 = 2^18
    const int BPB = 64;                 // fat blocks per batch
    const int f4pb = n4 / BPB;          // 4096 float4 per block
    int l2n4 = 0;
    while ((1 << l2n4) < n4) ++l2n4;

    dim3 fat(BPB, B, 1);
    dim3 blk(256, 1, 1);

    histgather_kernel<<<fat, blk, 0, stream>>>(
        (const float4*)cost, hist, meta, candv, candi, n4, f4pb);
    scan_kernel<<<B, 256, 0, stream>>>(hist, meta, K);
    fallback_gather_kernel<<<fat, blk, 0, stream>>>(
        (const float4*)cost, meta, candv, candi, n4, f4pb);
    solve_kernel<<<B, NT, 0, stream>>>(meta, candv, candi, K, N);

    const int s4 = srcN / 4, t4 = tgtN / 4;
    const int total4 = s4 + t4 + B * n4;
    final_kernel<<<(total4 + 255) / 256, blk, 0, stream>>>(
        (const float4*)src, (const float4*)tgt, (const float4*)cost,
        (float4*)out, meta, s4, t4, l2n4);
}

// Round 7
// 68.529 us; speedup vs baseline: 4.7805x; 1.0136x over previous
//
#include <hip/hip_runtime.h>
#include <stdint.h>

// ImportanceSparsification: per-batch top-k (k = 0.2*S*T) of 1/(cost+1e-8),
// out = (source, target, cost*mask). Exact selection with jax top_k
// tie-break (lowest flat index among equal importance values).
//
// R6 -> R7: the 33KB hipMemsetAsync(d_ws) was dispatched as rocclr
// fillBufferAligned costing ~48us per graph replay (~70% of total).
// Replaced with a 1-2us init kernel. No other changes.

static constexpr int HBINS = 512;     // linear cost bins
static constexpr int CAP   = 32768;   // per-batch candidate cap (global)
static constexpr int LCAP  = 1024;    // per-block candidate staging (LDS)
static constexpr int LDSCV = 12288;   // solve: LDS-staged candidate values
static constexpr int TIECAP = 2048;   // solve: LDS tie-index list cap
static constexpr int NT    = 512;     // solve block size
static constexpr int NW    = NT / 64; // waves in solve block
static constexpr uint32_t SPEC_LO = 100;  // speculative gather window (bins)
static constexpr uint32_t SPEC_HI = 104;
static constexpr float EPSF = 1e-8f;

__device__ __forceinline__ uint32_t impBits(float c) {
    // IEEE-correct f32 ops (no fast-math) -> bit-exact vs numpy reference
    return __float_as_uint(1.0f / (c + EPSF));
}

__device__ __forceinline__ uint32_t costBin(float x) {
    uint32_t bi = (uint32_t)(x * (float)HBINS);  // x in [0,1)
    return bi > (HBINS - 1) ? (HBINS - 1) : bi;
}

// meta per batch (16 u32):
// [0]=lo_bin [1]=hi_bin [2]=t [3]=base [4]=candcnt [5]=idxthr [7]=spec_ok

// ---- pass 0: zero hist + meta (replaces pathological hipMemsetAsync) ----
__global__ __launch_bounds__(256) void init_kernel(
    uint32_t* __restrict__ hist, uint32_t* __restrict__ meta, int B) {
    const int i = blockIdx.x * 256 + threadIdx.x;
    if (i < B * HBINS) hist[i] = 0u;
    if (i < B * 16) meta[i] = 0u;
}

// ---- pass 1: histogram + speculative candidate gather (one read pass) ----
__global__ __launch_bounds__(256) void histgather_kernel(
    const float4* __restrict__ cost4, uint32_t* __restrict__ hist,
    uint32_t* __restrict__ meta, uint32_t* __restrict__ candv,
    uint32_t* __restrict__ candi, int n4, int f4pb) {
    __shared__ uint32_t lh[HBINS];
    __shared__ uint32_t l_cv[LCAP];
    __shared__ uint32_t l_ci[LCAP];
    __shared__ uint32_t l_cnt, l_base;
    const int b = blockIdx.y;
    for (int i = threadIdx.x; i < HBINS; i += 256) lh[i] = 0;
    if (threadIdx.x == 0) l_cnt = 0;
    __syncthreads();
    const size_t base = (size_t)b * n4 + (size_t)blockIdx.x * f4pb;
    const uint32_t elem0 = (uint32_t)blockIdx.x * f4pb * 4u;
    const int iters = f4pb / 256;
    for (int it = 0; it < iters; ++it) {
        float4 v = cost4[base + it * 256 + threadIdx.x];
        const uint32_t e0 = elem0 + (uint32_t)(it * 256 + threadIdx.x) * 4u;
        const float x[4] = {v.x, v.y, v.z, v.w};
        #pragma unroll
        for (int j = 0; j < 4; ++j) {
            const uint32_t bi = costBin(x[j]);
            atomicAdd(&lh[bi], 1u);
            if (bi >= SPEC_LO && bi <= SPEC_HI) {
                const uint32_t p = atomicAdd(&l_cnt, 1u);
                if (p < (uint32_t)LCAP) {
                    l_cv[p] = __float_as_uint(x[j]);
                    l_ci[p] = e0 + (uint32_t)j;
                }
            }
        }
    }
    __syncthreads();
    uint32_t* gh = hist + (size_t)b * HBINS;
    for (int i = threadIdx.x; i < HBINS; i += 256)
        if (lh[i]) atomicAdd(&gh[i], lh[i]);
    const uint32_t n = (l_cnt > (uint32_t)LCAP) ? (uint32_t)LCAP : l_cnt;
    if (threadIdx.x == 0) l_base = atomicAdd(&meta[b * 16 + 4], n);
    __syncthreads();
    uint32_t* cv = candv + (size_t)b * CAP;
    uint32_t* ci = candi + (size_t)b * CAP;
    const uint32_t gb = l_base;
    for (uint32_t i = threadIdx.x; i < n; i += 256) {
        const uint32_t g = gb + i;
        if (g < (uint32_t)CAP) { cv[g] = l_cv[i]; ci[g] = l_ci[i]; }
    }
}

// ---- pass 2: prefix-scan 512 bins, locate K-th-smallest bin, validate ----
__global__ __launch_bounds__(256) void scan_kernel(
    const uint32_t* __restrict__ hist, uint32_t* __restrict__ meta, uint32_t K) {
    const int b = blockIdx.x;
    const uint32_t* h = hist + (size_t)b * HBINS;
    __shared__ uint32_t s[256];
    const int t = threadIdx.x;
    const int C = HBINS / 256;  // 2 bins per thread
    uint32_t hv[C];
    uint32_t csum = 0;
    for (int i = 0; i < C; ++i) { hv[i] = h[t * C + i]; csum += hv[i]; }
    s[t] = csum;
    __syncthreads();
    for (int off = 1; off < 256; off <<= 1) {
        uint32_t add = (t >= off) ? s[t - off] : 0u;
        uint32_t cur = s[t];
        __syncthreads();
        s[t] = cur + add;
        __syncthreads();
    }
    const uint32_t before = s[t] - csum;
    if (before < K && s[t] >= K) {
        uint32_t cum = before;
        for (int i = 0; i < C; ++i) {
            const uint32_t c = hv[i];
            if (cum + c >= K) {
                const uint32_t q = (uint32_t)(t * C + i);
                // accept only interior bins so the equal-importance plateau
                // (few ulps wide) cannot escape the gathered window
                if (q > SPEC_LO && q < SPEC_HI) {
                    meta[b * 16 + 0] = SPEC_LO;
                    meta[b * 16 + 1] = SPEC_HI;
                    meta[b * 16 + 3] = s[(SPEC_LO / C) - 1];  // bins < SPEC_LO
                    meta[b * 16 + 7] = 1u;
                } else {
                    const uint32_t lo = (q > 0) ? q - 1 : 0;
                    const uint32_t hi = (q < HBINS - 1) ? q + 1 : (HBINS - 1);
                    meta[b * 16 + 0] = lo;
                    meta[b * 16 + 1] = hi;
                    meta[b * 16 + 3] = cum - ((q > 0) ? h[q - 1] : 0u);
                    meta[b * 16 + 4] = 0u;
                    meta[b * 16 + 7] = 0u;
                }
                break;
            }
            cum += c;
        }
    }
}

// ---- pass 3 (normally no-op): exact gather when speculation missed ----
__global__ __launch_bounds__(256) void fallback_gather_kernel(
    const float4* __restrict__ cost4, uint32_t* __restrict__ meta,
    uint32_t* __restrict__ candv, uint32_t* __restrict__ candi,
    int n4, int f4pb) {
    const int b = blockIdx.y;
    if (meta[b * 16 + 7]) return;  // speculation hit
    __shared__ uint32_t l_cv[LCAP];
    __shared__ uint32_t l_ci[LCAP];
    __shared__ uint32_t l_cnt, l_base;
    const uint32_t lo = meta[b * 16 + 0];
    const uint32_t hi = meta[b * 16 + 1];
    if (threadIdx.x == 0) l_cnt = 0;
    __syncthreads();
    const size_t base = (size_t)b * n4 + (size_t)blockIdx.x * f4pb;
    const uint32_t elem0 = (uint32_t)blockIdx.x * f4pb * 4u;
    const int iters = f4pb / 256;
    for (int it = 0; it < iters; ++it) {
        float4 v = cost4[base + it * 256 + threadIdx.x];
        const uint32_t e0 = elem0 + (uint32_t)(it * 256 + threadIdx.x) * 4u;
        const float x[4] = {v.x, v.y, v.z, v.w};
        #pragma unroll
        for (int j = 0; j < 4; ++j) {
            const uint32_t bi = costBin(x[j]);
            if (bi >= lo && bi <= hi) {
                const uint32_t p = atomicAdd(&l_cnt, 1u);
                if (p < (uint32_t)LCAP) {
                    l_cv[p] = __float_as_uint(x[j]);
                    l_ci[p] = e0 + (uint32_t)j;
                }
            }
        }
    }
    __syncthreads();
    const uint32_t n = (l_cnt > (uint32_t)LCAP) ? (uint32_t)LCAP : l_cnt;
    if (threadIdx.x == 0) l_base = atomicAdd(&meta[b * 16 + 4], n);
    __syncthreads();
    uint32_t* cv = candv + (size_t)b * CAP;
    uint32_t* ci = candi + (size_t)b * CAP;
    const uint32_t gb = l_base;
    for (uint32_t i = threadIdx.x; i < n; i += 256) {
        const uint32_t g = gb + i;
        if (g < (uint32_t)CAP) { cv[g] = l_cv[i]; ci[g] = l_ci[i]; }
    }
}

// ---- pass 4: exact threshold + tie index via histogram descent ----
__global__ __launch_bounds__(NT) void solve_kernel(
    uint32_t* __restrict__ meta, const uint32_t* __restrict__ candv,
    const uint32_t* __restrict__ candi, uint32_t K, int N) {
    const int b = blockIdx.x;
    uint32_t* mb = meta + b * 16;
    const uint32_t cnt0 = mb[4];
    const uint32_t cnt = (cnt0 > (uint32_t)CAP) ? (uint32_t)CAP : cnt0;
    const uint32_t need0 = K - mb[3];  // rank of c_(K) among candidates
    const uint32_t* cv = candv + (size_t)b * CAP;
    const uint32_t* ci = candi + (size_t)b * CAP;
    __shared__ uint32_t scv[LDSCV];
    __shared__ uint32_t h[TIECAP];          // level hist / tie-index list
    __shared__ uint32_t sw[4 * NW];
    __shared__ uint32_t s_lo, s_need, s_range, s_tiecnt, s_res;
    const int t = threadIdx.x;
    const int w = t >> 6, ln = t & 63;

    // stage candidate values in LDS; block min/max of cost bits
    uint32_t mn = 0xFFFFFFFFu, mx = 0u;
    for (uint32_t j = t; j < cnt; j += NT) {
        const uint32_t v = cv[j];
        if (j < (uint32_t)LDSCV) scv[j] = v;
        mn = (v < mn) ? v : mn;
        mx = (v > mx) ? v : mx;
    }
    #pragma unroll
    for (int o = 1; o < 64; o <<= 1) {
        const uint32_t a = (uint32_t)__shfl_xor((int)mn, o);
        const uint32_t z = (uint32_t)__shfl_xor((int)mx, o);
        mn = (a < mn) ? a : mn;
        mx = (z > mx) ? z : mx;
    }
    if (ln == 0) { sw[w] = mn; sw[NW + w] = mx; }
    __syncthreads();
    uint32_t lo = sw[0], hix = sw[NW];
    #pragma unroll
    for (int i = 1; i < NW; ++i) {
        lo = (sw[i] < lo) ? sw[i] : lo;
        hix = (sw[NW + i] > hix) ? sw[NW + i] : hix;
    }
    uint32_t range = hix - lo + 1u;   // cost bits < 0x3F800000 -> no overflow
    uint32_t need = need0;

    // histogram descent: resolve exact need-th smallest cost-bit value
    while (range > 1u) {
        const int bits = 32 - __clz((int)(range - 1u));
        const int shift = (bits > 11) ? (bits - 11) : 0;
        for (int i = t; i < TIECAP; i += NT) h[i] = 0;
        __syncthreads();
        for (uint32_t j = t; j < cnt; j += NT) {
            const uint32_t v = (j < (uint32_t)LDSCV) ? scv[j] : cv[j];
            const uint32_t d = v - lo;
            if (v >= lo && d < range) atomicAdd(&h[d >> shift], 1u);
        }
        __syncthreads();
        // ascending prefix over 2048 bins (4 per thread)
        uint32_t hv[4];
        uint32_t csum = 0;
        #pragma unroll
        for (int i = 0; i < 4; ++i) { hv[i] = h[t * 4 + i]; csum += hv[i]; }
        uint32_t incl = csum;
        #pragma unroll
        for (int o = 1; o < 64; o <<= 1) {
            const uint32_t up = (uint32_t)__shfl_up((int)incl, o);
            if (ln >= o) incl += up;
        }
        if (ln == 63) sw[w] = incl;
        __syncthreads();
        uint32_t wpre = 0;
        for (int i = 0; i < w; ++i) wpre += sw[i];
        const uint32_t before = wpre + incl - csum;
        if (before < need && before + csum >= need) {
            uint32_t cum = before;
            #pragma unroll
            for (int i = 0; i < 4; ++i) {
                if (cum + hv[i] >= need) {
                    const uint32_t q = (uint32_t)(t * 4 + i);
                    const uint32_t off = q << shift;
                    s_lo = lo + off;
                    s_need = need - cum;
                    const uint32_t span = range - off;
                    s_range = (span < (1u << shift)) ? span : (1u << shift);
                    break;
                }
                cum += hv[i];
            }
        }
        __syncthreads();
        lo = s_lo; need = s_need; range = s_range;
        __syncthreads();
    }
    const uint32_t thr = impBits(__uint_as_float(lo));

    // count gt/eq; min/max tie index
    uint32_t cg = 0, ce = 0, imn = 0xFFFFFFFFu, imx = 0u;
    for (uint32_t j = t; j < cnt; j += NT) {
        const uint32_t v = (j < (uint32_t)LDSCV) ? scv[j] : cv[j];
        const uint32_t ib = impBits(__uint_as_float(v));
        if (ib > thr) cg++;
        else if (ib == thr) {
            ce++;
            const uint32_t ix = ci[j];
            imn = (ix < imn) ? ix : imn;
            imx = (ix > imx) ? ix : imx;
        }
    }
    #pragma unroll
    for (int o = 1; o < 64; o <<= 1) {
        cg += (uint32_t)__shfl_xor((int)cg, o);
        ce += (uint32_t)__shfl_xor((int)ce, o);
        const uint32_t a = (uint32_t)__shfl_xor((int)imn, o);
        const uint32_t z = (uint32_t)__shfl_xor((int)imx, o);
        imn = (a < imn) ? a : imn;
        imx = (z > imx) ? z : imx;
    }
    if (ln == 0) { sw[w] = cg; sw[NW + w] = ce; sw[2 * NW + w] = imn; sw[3 * NW + w] = imx; }
    __syncthreads();
    uint32_t gt = 0, eq = 0, imin = 0xFFFFFFFFu, imax = 0u;
    #pragma unroll
    for (int i = 0; i < NW; ++i) {
        gt += sw[i];
        eq += sw[NW + i];
        imin = (sw[2 * NW + i] < imin) ? sw[2 * NW + i] : imin;
        imax = (sw[3 * NW + i] > imax) ? sw[3 * NW + i] : imax;
    }
    __syncthreads();

    const uint32_t m = need0 - gt;  // # threshold-equal elements to take (>=1)
    uint32_t idxthr = 0xFFFFFFFFu;
    if (m < eq) {
        if (m == 1) {
            idxthr = imin;
        } else {
            // gather tie indices into LDS, O(eq) rank-select
            if (t == 0) s_tiecnt = 0;
            __syncthreads();
            for (uint32_t j = t; j < cnt; j += NT) {
                const uint32_t v = (j < (uint32_t)LDSCV) ? scv[j] : cv[j];
                if (impBits(__uint_as_float(v)) == thr) {
                    const uint32_t p = atomicAdd(&s_tiecnt, 1u);
                    if (p < (uint32_t)TIECAP) h[p] = ci[j];
                }
            }
            __syncthreads();
            const uint32_t tc = s_tiecnt;
            if (tc <= (uint32_t)TIECAP) {
                for (uint32_t p = t; p < tc; p += NT) {
                    const uint32_t x = h[p];
                    uint32_t r = 0;
                    for (uint32_t q2 = 0; q2 < tc; ++q2) r += (h[q2] < x) ? 1u : 0u;
                    if (r == m - 1) s_res = x;  // unique (flat indices distinct)
                }
                __syncthreads();
                idxthr = s_res;
            } else {
                // unreachable in practice: bsearch m-th smallest index
                uint32_t l2 = imin, h2 = imax;
                while (l2 < h2) {
                    const uint32_t mid = l2 + ((h2 - l2) >> 1);
                    uint32_t c = 0;
                    for (uint32_t j = t; j < cnt; j += NT) {
                        const uint32_t v = (j < (uint32_t)LDSCV) ? scv[j] : cv[j];
                        c += (impBits(__uint_as_float(v)) == thr && ci[j] <= mid) ? 1u : 0u;
                    }
                    #pragma unroll
                    for (int o = 1; o < 64; o <<= 1) c += (uint32_t)__shfl_xor((int)c, o);
                    if (ln == 0) sw[w] = c;
                    __syncthreads();
                    uint32_t tot = 0;
                    for (int i = 0; i < NW; ++i) tot += sw[i];
                    __syncthreads();
                    if (tot >= m) h2 = mid; else l2 = mid + 1;
                }
                idxthr = l2;
            }
        }
    }
    if (t == 0) { mb[2] = thr; mb[5] = idxthr; }
}

// ---- pass 5: fused output (src copy | tgt copy | masked cost) ----
__global__ __launch_bounds__(256) void final_kernel(
    const float4* __restrict__ src4, const float4* __restrict__ tgt4,
    const float4* __restrict__ cost4, float4* __restrict__ out4,
    const uint32_t* __restrict__ meta, int s4, int t4, int l2n4) {
    const int idx = blockIdx.x * 256 + threadIdx.x;
    if (idx < s4) { out4[idx] = src4[idx]; return; }
    int r = idx - s4;
    if (r < t4) { out4[idx] = tgt4[r]; return; }
    r -= t4;
    const int b = r >> l2n4;
    const uint32_t t = meta[b * 16 + 2];
    const uint32_t idxthr = meta[b * 16 + 5];
    const int i = r & ((1 << l2n4) - 1);
    float4 v = cost4[(size_t)b * (1 << l2n4) + i];
    const uint32_t base = (uint32_t)i * 4u;
    float4 o;
    uint32_t bx;
    bx = impBits(v.x); o.x = (bx > t || (bx == t && base + 0 <= idxthr)) ? v.x : 0.0f;
    bx = impBits(v.y); o.y = (bx > t || (bx == t && base + 1 <= idxthr)) ? v.y : 0.0f;
    bx = impBits(v.z); o.z = (bx > t || (bx == t && base + 2 <= idxthr)) ? v.z : 0.0f;
    bx = impBits(v.w); o.w = (bx > t || (bx == t && base + 3 <= idxthr)) ? v.w : 0.0f;
    out4[idx] = o;
}

extern "C" void kernel_launch(void* const* d_in, const int* in_sizes, int n_in,
                              void* d_out, int out_size, void* d_ws, size_t ws_size,
                              hipStream_t stream) {
    const float* src  = (const float*)d_in[0];
    const float* tgt  = (const float*)d_in[1];
    const float* cost = (const float*)d_in[2];
    const int srcN = in_sizes[0];
    const int tgtN = in_sizes[1];
    const int costN = in_sizes[2];
    const int S = 1024, T = 1024;
    const int N = S * T;
    const int B = costN / N;
    const uint32_t K = (uint32_t)(((uint64_t)N * 2ull) / 10ull);  // int(N*0.2)

    float* out = (float*)d_out;

    uint32_t* hist  = (uint32_t*)d_ws;
    uint32_t* meta  = hist + (size_t)B * HBINS;
    uint32_t* candv = meta + (size_t)B * 16;
    uint32_t* candi = candv + (size_t)B * CAP;

    const int n4 = N / 4;               // 262144 = 2^18
    const int BPB = 64;                 // fat blocks per batch
    const int f4pb = n4 / BPB;          // 4096 float4 per block
    int l2n4 = 0;
    while ((1 << l2n4) < n4) ++l2n4;

    dim3 fat(BPB, B, 1);
    dim3 blk(256, 1, 1);

    init_kernel<<<(B * HBINS + 255) / 256, blk, 0, stream>>>(hist, meta, B);
    histgather_kernel<<<fat, blk, 0, stream>>>(
        (const float4*)cost, hist, meta, candv, candi, n4, f4pb);
    scan_kernel<<<B, 256, 0, stream>>>(hist, meta, K);
    fallback_gather_kernel<<<fat, blk, 0, stream>>>(
        (const float4*)cost, meta, candv, candi, n4, f4pb);
    solve_kernel<<<B, NT, 0, stream>>>(meta, candv, candi, K, N);

    const int s4 = srcN / 4, t4 = tgtN / 4;
    const int total4 = s4 + t4 + B * n4;
    final_kernel<<<(total4 + 255) / 256, blk, 0, stream>>>(
        (const float4*)src, (const float4*)tgt, (const float4*)cost,
        (float4*)out, meta, s4, t4, l2n4);
}

// Round 8
// 64.022 us; speedup vs baseline: 5.1171x; 1.0704x over previous
//
#include <hip/hip_runtime.h>
#include <stdint.h>

// ImportanceSparsification: per-batch top-k (k = 0.2*S*T) of 1/(cost+1e-8),
// out = (source, target, cost*mask). Exact selection with jax top_k
// tie-break (lowest flat index among equal importance values).
//
// R7 -> R8: 6 kernels -> 4. scan + spec-miss fallback folded into solve
// (512-thread in-register prefix scan; slow-path re-gather inside solve,
// never taken on uniform data but exact). src/tgt copies folded into
// histgather as copy-role blocks (overlaps 32MB copy with the hist pass).
// final masks cost only. Descent loop got termination guards.

static constexpr int HBINS = 512;     // linear cost bins
static constexpr int CAP   = 32768;   // per-batch candidate cap (global)
static constexpr int LCAP  = 1024;    // per-block candidate staging (LDS)
static constexpr int LDSCV = 12288;   // solve: LDS-staged candidate values
static constexpr int TIECAP = 2048;   // solve: LDS tie-index list cap
static constexpr int NT    = 512;     // solve block size
static constexpr int NW    = NT / 64; // waves in solve block
static constexpr int BPB   = 64;      // hist blocks per batch (log2 = 6)
static constexpr int CPB   = 256;     // copy-role blocks
static constexpr uint32_t SPEC_LO = 100;  // speculative gather window (bins)
static constexpr uint32_t SPEC_HI = 104;
static constexpr float EPSF = 1e-8f;

__device__ __forceinline__ uint32_t impBits(float c) {
    // IEEE-correct f32 ops (no fast-math) -> bit-exact vs numpy reference
    return __float_as_uint(1.0f / (c + EPSF));
}

__device__ __forceinline__ uint32_t costBin(float x) {
    uint32_t bi = (uint32_t)(x * (float)HBINS);  // x in [0,1)
    return bi > (HBINS - 1) ? (HBINS - 1) : bi;
}

// meta per batch (16 u32): [2]=thr [4]=candcnt [5]=idxthr

// ---- pass 0: zero hist + meta ----
__global__ __launch_bounds__(256) void init_kernel(
    uint32_t* __restrict__ hist, uint32_t* __restrict__ meta, int B) {
    const int i = blockIdx.x * 256 + threadIdx.x;
    if (i < B * HBINS) hist[i] = 0u;
    if (i < B * 16) meta[i] = 0u;
}

// ---- pass 1: histogram + speculative gather; copy-role blocks move src/tgt ----
__global__ __launch_bounds__(256) void histgather_kernel(
    const float4* __restrict__ cost4, const float4* __restrict__ src4,
    const float4* __restrict__ tgt4, float4* __restrict__ out4,
    uint32_t* __restrict__ hist, uint32_t* __restrict__ meta,
    uint32_t* __restrict__ candv, uint32_t* __restrict__ candi,
    int n4, int f4pb, int nHist, int s4, int t4, int c4pb) {
    __shared__ uint32_t lh[HBINS];
    __shared__ uint32_t l_cv[LCAP];
    __shared__ uint32_t l_ci[LCAP];
    __shared__ uint32_t l_cnt, l_base;
    const int bid = blockIdx.x;
    if (bid >= nHist) {
        // copy role: out[0:s4) = src, out[s4:s4+t4) = tgt
        const int cid = bid - nHist;
        const int tot = s4 + t4;
        const int i0 = cid * c4pb;
        int i1 = i0 + c4pb; if (i1 > tot) i1 = tot;
        for (int i = i0 + threadIdx.x; i < i1; i += 256)
            out4[i] = (i < s4) ? src4[i] : tgt4[i - s4];
        return;
    }
    const int b = bid >> 6;          // BPB = 64
    const int x = bid & (BPB - 1);
    for (int i = threadIdx.x; i < HBINS; i += 256) lh[i] = 0;
    if (threadIdx.x == 0) l_cnt = 0;
    __syncthreads();
    const size_t base = (size_t)b * n4 + (size_t)x * f4pb;
    const uint32_t elem0 = (uint32_t)x * f4pb * 4u;
    const int iters = f4pb / 256;
    for (int it = 0; it < iters; ++it) {
        float4 v = cost4[base + it * 256 + threadIdx.x];
        const uint32_t e0 = elem0 + (uint32_t)(it * 256 + threadIdx.x) * 4u;
        const float xx[4] = {v.x, v.y, v.z, v.w};
        #pragma unroll
        for (int j = 0; j < 4; ++j) {
            const uint32_t bi = costBin(xx[j]);
            atomicAdd(&lh[bi], 1u);
            if (bi >= SPEC_LO && bi <= SPEC_HI) {
                const uint32_t p = atomicAdd(&l_cnt, 1u);
                if (p < (uint32_t)LCAP) {
                    l_cv[p] = __float_as_uint(xx[j]);
                    l_ci[p] = e0 + (uint32_t)j;
                }
            }
        }
    }
    __syncthreads();
    uint32_t* gh = hist + (size_t)b * HBINS;
    for (int i = threadIdx.x; i < HBINS; i += 256)
        if (lh[i]) atomicAdd(&gh[i], lh[i]);
    const uint32_t n = (l_cnt > (uint32_t)LCAP) ? (uint32_t)LCAP : l_cnt;
    if (threadIdx.x == 0) l_base = atomicAdd(&meta[b * 16 + 4], n);
    __syncthreads();
    uint32_t* cv = candv + (size_t)b * CAP;
    uint32_t* ci = candi + (size_t)b * CAP;
    const uint32_t gb = l_base;
    for (uint32_t i = threadIdx.x; i < n; i += 256) {
        const uint32_t g = gb + i;
        if (g < (uint32_t)CAP) { cv[g] = l_cv[i]; ci[g] = l_ci[i]; }
    }
}

// ---- pass 2: integrated scan + exact threshold + tie index ----
__global__ __launch_bounds__(NT) void solve_kernel(
    const uint32_t* __restrict__ hist, uint32_t* __restrict__ meta,
    uint32_t* __restrict__ candv, uint32_t* __restrict__ candi,
    const float4* __restrict__ cost4, int n4, uint32_t K, int N) {
    const int b = blockIdx.x;
    uint32_t* mb = meta + b * 16;
    const uint32_t* cv = candv + (size_t)b * CAP;
    const uint32_t* ci = candi + (size_t)b * CAP;
    __shared__ uint32_t scv[LDSCV];
    __shared__ uint32_t hh[TIECAP];         // level hist / tie-index list
    __shared__ uint32_t pref[HBINS];
    __shared__ uint32_t sw[4 * NW];
    __shared__ uint32_t s_q, s_lo, s_need, s_range, s_tiecnt, s_res, s_cnt;
    const int t = threadIdx.x;
    const int w = t >> 6, ln = t & 63;

    // -- scan: 512 bins, one per thread; inclusive prefix --
    const uint32_t hv = hist[(size_t)b * HBINS + t];
    uint32_t incl = hv;
    #pragma unroll
    for (int o = 1; o < 64; o <<= 1) {
        const uint32_t u = (uint32_t)__shfl_up((int)incl, o);
        if (ln >= o) incl += u;
    }
    if (ln == 63) sw[w] = incl;
    if (t == 0) s_q = HBINS - 1;
    __syncthreads();
    uint32_t wbase = 0;
    for (int i = 0; i < w; ++i) wbase += sw[i];
    incl += wbase;
    pref[t] = incl;
    __syncthreads();
    if (K > incl - hv && K <= incl) s_q = (uint32_t)t;  // unique crossing
    __syncthreads();
    const uint32_t q = s_q;

    uint32_t cnt, need0;
    if (q > SPEC_LO && q < SPEC_HI) {
        // speculation hit: interior bin -> equal-importance plateau (few
        // ulps wide) strictly inside gathered window [SPEC_LO, SPEC_HI]
        need0 = K - pref[SPEC_LO - 1];
        const uint32_t c0 = mb[4];
        cnt = (c0 > (uint32_t)CAP) ? (uint32_t)CAP : c0;
    } else {
        // slow path (not taken for uniform data): exact re-gather of
        // window [q-1, q+1] by this block alone
        const uint32_t lob = (q > 0) ? q - 1 : 0;
        const uint32_t hib = (q < HBINS - 1) ? q + 1 : (HBINS - 1);
        need0 = K - ((lob > 0) ? pref[lob - 1] : 0u);
        if (t == 0) s_cnt = 0;
        __syncthreads();
        uint32_t* wcv = candv + (size_t)b * CAP;
        uint32_t* wci = candi + (size_t)b * CAP;
        for (uint32_t i4 = (uint32_t)t; i4 < (uint32_t)n4; i4 += NT) {
            const float4 v = cost4[(size_t)b * n4 + i4];
            const float xx[4] = {v.x, v.y, v.z, v.w};
            #pragma unroll
            for (int j = 0; j < 4; ++j) {
                const uint32_t bi = costBin(xx[j]);
                if (bi >= lob && bi <= hib) {
                    const uint32_t p = atomicAdd(&s_cnt, 1u);
                    if (p < (uint32_t)CAP) {
                        wcv[p] = __float_as_uint(xx[j]);
                        wci[p] = i4 * 4u + (uint32_t)j;
                    }
                }
            }
        }
        __syncthreads();
        cnt = (s_cnt > (uint32_t)CAP) ? (uint32_t)CAP : s_cnt;
    }

    // -- stage candidate values in LDS; block min/max of cost bits --
    uint32_t mn = 0xFFFFFFFFu, mx = 0u;
    for (uint32_t j = t; j < cnt; j += NT) {
        const uint32_t v = cv[j];
        if (j < (uint32_t)LDSCV) scv[j] = v;
        mn = (v < mn) ? v : mn;
        mx = (v > mx) ? v : mx;
    }
    #pragma unroll
    for (int o = 1; o < 64; o <<= 1) {
        const uint32_t a = (uint32_t)__shfl_xor((int)mn, o);
        const uint32_t z = (uint32_t)__shfl_xor((int)mx, o);
        mn = (a < mn) ? a : mn;
        mx = (z > mx) ? z : mx;
    }
    if (ln == 0) { sw[w] = mn; sw[NW + w] = mx; }
    __syncthreads();
    uint32_t lo = sw[0], hix = sw[NW];
    #pragma unroll
    for (int i = 1; i < NW; ++i) {
        lo = (sw[i] < lo) ? sw[i] : lo;
        hix = (sw[NW + i] > hix) ? sw[NW + i] : hix;
    }
    uint32_t range = hix - lo + 1u;
    uint32_t need = need0;

    // -- histogram descent: exact need-th smallest cost-bit value --
    while (range > 1u) {
        const int bits = 32 - __clz((int)(range - 1u));
        const int shift = (bits > 11) ? (bits - 11) : 0;
        for (int i = t; i < TIECAP; i += NT) hh[i] = 0;
        __syncthreads();
        for (uint32_t j = t; j < cnt; j += NT) {
            const uint32_t v = (j < (uint32_t)LDSCV) ? scv[j] : cv[j];
            const uint32_t d = v - lo;
            if (v >= lo && d < range) atomicAdd(&hh[d >> shift], 1u);
        }
        __syncthreads();
        uint32_t hv4[4];
        uint32_t csum = 0;
        #pragma unroll
        for (int i = 0; i < 4; ++i) { hv4[i] = hh[t * 4 + i]; csum += hv4[i]; }
        uint32_t inc2 = csum;
        #pragma unroll
        for (int o = 1; o < 64; o <<= 1) {
            const uint32_t up = (uint32_t)__shfl_up((int)inc2, o);
            if (ln >= o) inc2 += up;
        }
        if (ln == 63) sw[w] = inc2;
        // termination guard: defaults in case no crossing (corrupt input)
        if (t == 0) { s_lo = lo; s_need = 1u; s_range = 1u; }
        __syncthreads();
        uint32_t wpre = 0;
        for (int i = 0; i < w; ++i) wpre += sw[i];
        const uint32_t before = wpre + inc2 - csum;
        if (before < need && before + csum >= need) {
            uint32_t cum = before;
            #pragma unroll
            for (int i = 0; i < 4; ++i) {
                if (cum + hv4[i] >= need) {
                    const uint32_t qq = (uint32_t)(t * 4 + i);
                    const uint32_t off = qq << shift;
                    s_lo = lo + off;
                    s_need = need - cum;
                    const uint32_t span = range - off;
                    s_range = (span < (1u << shift)) ? span : (1u << shift);
                    break;
                }
                cum += hv4[i];
            }
        }
        __syncthreads();
        lo = s_lo; need = s_need; range = s_range;
        __syncthreads();
    }
    const uint32_t thr = impBits(__uint_as_float(lo));

    // -- count gt/eq; min/max tie index --
    uint32_t cg = 0, ce = 0, imn = 0xFFFFFFFFu, imx = 0u;
    for (uint32_t j = t; j < cnt; j += NT) {
        const uint32_t v = (j < (uint32_t)LDSCV) ? scv[j] : cv[j];
        const uint32_t ib = impBits(__uint_as_float(v));
        if (ib > thr) cg++;
        else if (ib == thr) {
            ce++;
            const uint32_t ix = ci[j];
            imn = (ix < imn) ? ix : imn;
            imx = (ix > imx) ? ix : imx;
        }
    }
    #pragma unroll
    for (int o = 1; o < 64; o <<= 1) {
        cg += (uint32_t)__shfl_xor((int)cg, o);
        ce += (uint32_t)__shfl_xor((int)ce, o);
        const uint32_t a = (uint32_t)__shfl_xor((int)imn, o);
        const uint32_t z = (uint32_t)__shfl_xor((int)imx, o);
        imn = (a < imn) ? a : imn;
        imx = (z > imx) ? z : imx;
    }
    if (ln == 0) { sw[w] = cg; sw[NW + w] = ce; sw[2 * NW + w] = imn; sw[3 * NW + w] = imx; }
    __syncthreads();
    uint32_t gt = 0, eq = 0, imin = 0xFFFFFFFFu, imax = 0u;
    #pragma unroll
    for (int i = 0; i < NW; ++i) {
        gt += sw[i];
        eq += sw[NW + i];
        imin = (sw[2 * NW + i] < imin) ? sw[2 * NW + i] : imin;
        imax = (sw[3 * NW + i] > imax) ? sw[3 * NW + i] : imax;
    }
    __syncthreads();

    const uint32_t m = need0 - gt;  // # threshold-equal elements to take
    uint32_t idxthr = 0xFFFFFFFFu;
    if (m < eq) {
        if (m == 1) {
            idxthr = imin;
        } else {
            // gather tie indices into LDS, O(eq) rank-select
            if (t == 0) { s_tiecnt = 0; s_res = imin; }
            __syncthreads();
            for (uint32_t j = t; j < cnt; j += NT) {
                const uint32_t v = (j < (uint32_t)LDSCV) ? scv[j] : cv[j];
                if (impBits(__uint_as_float(v)) == thr) {
                    const uint32_t p = atomicAdd(&s_tiecnt, 1u);
                    if (p < (uint32_t)TIECAP) hh[p] = ci[j];
                }
            }
            __syncthreads();
            const uint32_t tc = s_tiecnt;
            if (tc <= (uint32_t)TIECAP) {
                for (uint32_t p = t; p < tc; p += NT) {
                    const uint32_t x = hh[p];
                    uint32_t r = 0;
                    for (uint32_t q2 = 0; q2 < tc; ++q2) r += (hh[q2] < x) ? 1u : 0u;
                    if (r == m - 1) s_res = x;  // unique (flat indices distinct)
                }
                __syncthreads();
                idxthr = s_res;
            } else {
                // unreachable in practice: bsearch m-th smallest index
                uint32_t l2 = imin, h2 = imax;
                while (l2 < h2) {
                    const uint32_t mid = l2 + ((h2 - l2) >> 1);
                    uint32_t c = 0;
                    for (uint32_t j = t; j < cnt; j += NT) {
                        const uint32_t v = (j < (uint32_t)LDSCV) ? scv[j] : cv[j];
                        c += (impBits(__uint_as_float(v)) == thr && ci[j] <= mid) ? 1u : 0u;
                    }
                    #pragma unroll
                    for (int o = 1; o < 64; o <<= 1) c += (uint32_t)__shfl_xor((int)c, o);
                    if (ln == 0) sw[w] = c;
                    __syncthreads();
                    uint32_t tot = 0;
                    for (int i = 0; i < NW; ++i) tot += sw[i];
                    __syncthreads();
                    if (tot >= m) h2 = mid; else l2 = mid + 1;
                }
                idxthr = l2;
            }
        }
    }
    if (t == 0) { mb[2] = thr; mb[5] = idxthr; }
}

// ---- pass 3: masked cost write ----
__global__ __launch_bounds__(256) void final_kernel(
    const float4* __restrict__ cost4, float4* __restrict__ outc4,
    const uint32_t* __restrict__ meta, int l2n4) {
    const int idx = blockIdx.x * 256 + threadIdx.x;
    const int b = idx >> l2n4;
    const uint32_t t = meta[b * 16 + 2];
    const uint32_t idxthr = meta[b * 16 + 5];
    const int i = idx & ((1 << l2n4) - 1);
    float4 v = cost4[idx];
    const uint32_t base = (uint32_t)i * 4u;
    float4 o;
    uint32_t bx;
    bx = impBits(v.x); o.x = (bx > t || (bx == t && base + 0 <= idxthr)) ? v.x : 0.0f;
    bx = impBits(v.y); o.y = (bx > t || (bx == t && base + 1 <= idxthr)) ? v.y : 0.0f;
    bx = impBits(v.z); o.z = (bx > t || (bx == t && base + 2 <= idxthr)) ? v.z : 0.0f;
    bx = impBits(v.w); o.w = (bx > t || (bx == t && base + 3 <= idxthr)) ? v.w : 0.0f;
    outc4[idx] = o;
}

extern "C" void kernel_launch(void* const* d_in, const int* in_sizes, int n_in,
                              void* d_out, int out_size, void* d_ws, size_t ws_size,
                              hipStream_t stream) {
    const float* src  = (const float*)d_in[0];
    const float* tgt  = (const float*)d_in[1];
    const float* cost = (const float*)d_in[2];
    const int srcN = in_sizes[0];
    const int tgtN = in_sizes[1];
    const int costN = in_sizes[2];
    const int S = 1024, T = 1024;
    const int N = S * T;
    const int B = costN / N;
    const uint32_t K = (uint32_t)(((uint64_t)N * 2ull) / 10ull);  // int(N*0.2)

    float* out = (float*)d_out;

    uint32_t* hist  = (uint32_t*)d_ws;
    uint32_t* meta  = hist + (size_t)B * HBINS;
    uint32_t* candv = meta + (size_t)B * 16;
    uint32_t* candi = candv + (size_t)B * CAP;

    const int n4 = N / 4;               // 262144 = 2^18
    const int f4pb = n4 / BPB;          // 4096 float4 per hist block
    int l2n4 = 0;
    while ((1 << l2n4) < n4) ++l2n4;

    const int s4 = srcN / 4, t4 = tgtN / 4;
    const int nHist = B * BPB;
    const int c4pb = (s4 + t4 + CPB - 1) / CPB;

    dim3 blk(256, 1, 1);

    init_kernel<<<(B * HBINS + 255) / 256, blk, 0, stream>>>(hist, meta, B);
    histgather_kernel<<<nHist + CPB, blk, 0, stream>>>(
        (const float4*)cost, (const float4*)src, (const float4*)tgt,
        (float4*)out, hist, meta, candv, candi, n4, f4pb, nHist, s4, t4, c4pb);
    solve_kernel<<<B, NT, 0, stream>>>(hist, meta, candv, candi,
                                       (const float4*)cost, n4, K, N);
    final_kernel<<<(B * n4) / 256, blk, 0, stream>>>(
        (const float4*)cost, (float4*)out + s4 + t4, meta, l2n4);
}